// Round 1
// baseline (21291.676 us; speedup 1.0000x reference)
//
#include <hip/hip_runtime.h>
#include <hip/hip_bf16.h>
#include <math.h>

#define B_  4096
#define L_  30
#define WD_ 300
#define H_  20
#define AD_ 20
#define MD_ 400
#define E_  10
#define ED_ 100
#define QD_ 200
#define CD_ 50
#define SD_ 50

__device__ __forceinline__ float wave_reduce_sum(float v) {
  #pragma unroll
  for (int off = 32; off > 0; off >>= 1) v += __shfl_xor(v, off);
  return v;
}

// ---------------------------------------------------------------------------
// Word branch: per-news fused MHA (20 heads) -> LayerNorm -> additive attn
// One block per news item b. LDS ~95 KB -> 1 block/CU on gfx950 (160 KB LDS).
// ---------------------------------------------------------------------------
__global__ __launch_bounds__(256) void word_branch_kernel(
    const float* __restrict__ X,                       // [B, L, WD]
    const float* __restrict__ wq, const float* __restrict__ bq,
    const float* __restrict__ wk, const float* __restrict__ bk,
    const float* __restrict__ wv, const float* __restrict__ bv,
    const float* __restrict__ ln_g, const float* __restrict__ ln_b,
    const float* __restrict__ wa_w, const float* __restrict__ wa_b,
    const float* __restrict__ wa_q,
    float* __restrict__ word_rep)                      // [B, MD]
{
  __shared__ float sX[L_][WD_];      // 36.0 KB
  __shared__ float sOut[L_][MD_];    // 48.0 KB
  __shared__ float sQ[L_][AD_];      // 2.4 KB
  __shared__ float sK[L_][AD_];      // 2.4 KB
  __shared__ float sV[L_][AD_];      // 2.4 KB
  __shared__ float sS[L_][32];       // 3.84 KB (pad to 32)
  __shared__ float sSc[L_];
  __shared__ float sAlpha[L_];

  const int b   = blockIdx.x;
  const int tid = threadIdx.x;

  const float* xb = X + (size_t)b * (L_ * WD_);
  for (int i = tid; i < L_ * WD_; i += 256) sX[i / WD_][i % WD_] = xb[i];
  __syncthreads();

  // ---- multi-head self-attention, head by head ----
  for (int h = 0; h < H_; ++h) {
    // q/k/v for this head: 3*30*20 = 1800 outputs, 300-MAC dot each
    for (int id = tid; id < 3 * L_ * AD_; id += 256) {
      const int which = id / (L_ * AD_);
      const int rem   = id - which * (L_ * AD_);
      const int l     = rem / AD_;
      const int d     = rem - l * AD_;
      const float* w    = (which == 0) ? wq : (which == 1) ? wk : wv;
      const float* bias = (which == 0) ? bq : (which == 1) ? bk : bv;
      const int col = h * AD_ + d;
      const float* xr = sX[l];
      float a0 = 0.f, a1 = 0.f, a2 = 0.f, a3 = 0.f;
      for (int k = 0; k < WD_; k += 4) {
        a0 += xr[k + 0] * w[(k + 0) * MD_ + col];
        a1 += xr[k + 1] * w[(k + 1) * MD_ + col];
        a2 += xr[k + 2] * w[(k + 2) * MD_ + col];
        a3 += xr[k + 3] * w[(k + 3) * MD_ + col];
      }
      const float r = (a0 + a1) + (a2 + a3) + bias[col];
      float* dst = (which == 0) ? &sQ[l][d] : (which == 1) ? &sK[l][d] : &sV[l][d];
      *dst = r;
    }
    __syncthreads();

    // scores[l][m] = (q . k) / sqrt(20)
    for (int id = tid; id < L_ * L_; id += 256) {
      const int l = id / L_;
      const int m = id - l * L_;
      float acc = 0.f;
      #pragma unroll
      for (int d = 0; d < AD_; ++d) acc += sQ[l][d] * sK[m][d];
      sS[l][m] = acc * 0.2236067977499790f;  // 1/sqrt(20)
    }
    __syncthreads();

    // row softmax (30 rows, one thread each; tiny)
    if (tid < L_) {
      float mx = -1e30f;
      for (int m = 0; m < L_; ++m) mx = fmaxf(mx, sS[tid][m]);
      float sum = 0.f;
      for (int m = 0; m < L_; ++m) { float e = __expf(sS[tid][m] - mx); sS[tid][m] = e; sum += e; }
      const float inv = 1.f / sum;
      for (int m = 0; m < L_; ++m) sS[tid][m] *= inv;
    }
    __syncthreads();

    // out[l][h*20+d] = attn @ v
    for (int id = tid; id < L_ * AD_; id += 256) {
      const int l = id / AD_;
      const int d = id - l * AD_;
      float acc = 0.f;
      #pragma unroll
      for (int m = 0; m < L_; ++m) acc += sS[l][m] * sV[m][d];
      sOut[l][h * AD_ + d] = acc;
    }
    __syncthreads();
  }

  // ---- LayerNorm over MD=400, one wave per row ----
  const int wave = tid >> 6, lane = tid & 63;
  for (int r = wave; r < L_; r += 4) {
    float s = 0.f, s2 = 0.f;
    for (int d = lane; d < MD_; d += 64) { const float v = sOut[r][d]; s += v; s2 += v * v; }
    s  = wave_reduce_sum(s);
    s2 = wave_reduce_sum(s2);
    const float mu  = s * (1.f / MD_);
    const float var = s2 * (1.f / MD_) - mu * mu;
    const float inv = rsqrtf(var + 1e-5f);
    for (int d = lane; d < MD_; d += 64)
      sOut[r][d] = (sOut[r][d] - mu) * inv * ln_g[d] + ln_b[d];
  }
  if (tid < L_) sSc[tid] = 0.f;
  __syncthreads();

  // ---- additive attention: s[l] = tanh(out @ wa_w + wa_b) . wa_q ----
  for (int id = tid; id < L_ * QD_; id += 256) {
    const int l = id / QD_;
    const int q = id - l * QD_;
    float acc = wa_b[q];
    #pragma unroll 4
    for (int d = 0; d < MD_; ++d) acc += sOut[l][d] * wa_w[d * QD_ + q];
    atomicAdd(&sSc[l], tanhf(acc) * wa_q[q]);
  }
  __syncthreads();
  if (tid == 0) {
    float mx = -1e30f;
    for (int l = 0; l < L_; ++l) mx = fmaxf(mx, sSc[l]);
    float sum = 0.f;
    for (int l = 0; l < L_; ++l) { float e = __expf(sSc[l] - mx); sAlpha[l] = e; sum += e; }
    const float inv = 1.f / sum;
    for (int l = 0; l < L_; ++l) sAlpha[l] *= inv;
  }
  __syncthreads();
  for (int d = tid; d < MD_; d += 256) {
    float acc = 0.f;
    #pragma unroll
    for (int l = 0; l < L_; ++l) acc += sAlpha[l] * sOut[l][d];
    word_rep[(size_t)b * MD_ + d] = tanhf(acc);
  }
}

// ---------------------------------------------------------------------------
// Entity branch: fc3 -> GCN -> LayerNorm -> additive attn. One block per b.
// ---------------------------------------------------------------------------
__global__ __launch_bounds__(256) void entity_branch_kernel(
    const float* __restrict__ Ein,                     // [B, E, ED]
    const float* __restrict__ fc3_w, const float* __restrict__ fc3_b,
    const float* __restrict__ gcn_A, const float* __restrict__ gcn_w, const float* __restrict__ gcn_b,
    const float* __restrict__ ln_g, const float* __restrict__ ln_b,
    const float* __restrict__ ea_w, const float* __restrict__ ea_b, const float* __restrict__ ea_q,
    float* __restrict__ ent_rep)                       // [B, MD]
{
  __shared__ float sRaw[E_][ED_];   // 4 KB (raw input, later reused for g)
  __shared__ float sE[E_][ED_];     // 4 KB
  __shared__ float sR[E_][MD_];     // 16 KB
  __shared__ float sA[E_][E_];
  __shared__ float sSc[E_];
  __shared__ float sAlpha[E_];

  const int b   = blockIdx.x;
  const int tid = threadIdx.x;
  const float* eb = Ein + (size_t)b * (E_ * ED_);
  for (int i = tid; i < E_ * ED_; i += 256) sRaw[i / ED_][i % ED_] = eb[i];
  if (tid < E_ * E_) sA[tid / E_][tid % E_] = gcn_A[tid];
  __syncthreads();

  // e = tanh(raw @ fc3_w + fc3_b)
  for (int id = tid; id < E_ * ED_; id += 256) {
    const int i = id / ED_, d = id - (id / ED_) * ED_;
    float acc = fc3_b[d];
    #pragma unroll 4
    for (int k = 0; k < ED_; ++k) acc += sRaw[i][k] * fc3_w[k * ED_ + d];
    sE[i][d] = tanhf(acc);
  }
  __syncthreads();
  // g = A @ e (over entity axis), reuse sRaw
  for (int id = tid; id < E_ * ED_; id += 256) {
    const int i = id / ED_, d = id - (id / ED_) * ED_;
    float acc = 0.f;
    #pragma unroll
    for (int f = 0; f < E_; ++f) acc += sA[i][f] * sE[f][d];
    sRaw[i][d] = acc;
  }
  __syncthreads();
  // r = relu(g @ gcn_w + gcn_b)
  for (int id = tid; id < E_ * MD_; id += 256) {
    const int i = id / MD_, d = id - (id / MD_) * MD_;
    float acc = gcn_b[d];
    #pragma unroll 4
    for (int k = 0; k < ED_; ++k) acc += sRaw[i][k] * gcn_w[k * MD_ + d];
    sR[i][d] = fmaxf(acc, 0.f);
  }
  __syncthreads();

  // LayerNorm rows
  const int wave = tid >> 6, lane = tid & 63;
  for (int r = wave; r < E_; r += 4) {
    float s = 0.f, s2 = 0.f;
    for (int d = lane; d < MD_; d += 64) { const float v = sR[r][d]; s += v; s2 += v * v; }
    s  = wave_reduce_sum(s);
    s2 = wave_reduce_sum(s2);
    const float mu  = s * (1.f / MD_);
    const float var = s2 * (1.f / MD_) - mu * mu;
    const float inv = rsqrtf(var + 1e-5f);
    for (int d = lane; d < MD_; d += 64)
      sR[r][d] = (sR[r][d] - mu) * inv * ln_g[d] + ln_b[d];
  }
  if (tid < E_) sSc[tid] = 0.f;
  __syncthreads();

  // additive attention over E entities
  for (int id = tid; id < E_ * QD_; id += 256) {
    const int i = id / QD_, q = id - (id / QD_) * QD_;
    float acc = ea_b[q];
    #pragma unroll 4
    for (int d = 0; d < MD_; ++d) acc += sR[i][d] * ea_w[d * QD_ + q];
    atomicAdd(&sSc[i], tanhf(acc) * ea_q[q]);
  }
  __syncthreads();
  if (tid == 0) {
    float mx = -1e30f;
    for (int i = 0; i < E_; ++i) mx = fmaxf(mx, sSc[i]);
    float sum = 0.f;
    for (int i = 0; i < E_; ++i) { float e = __expf(sSc[i] - mx); sAlpha[i] = e; sum += e; }
    const float inv = 1.f / sum;
    for (int i = 0; i < E_; ++i) sAlpha[i] *= inv;
  }
  __syncthreads();
  for (int d = tid; d < MD_; d += 256) {
    float acc = 0.f;
    #pragma unroll
    for (int i = 0; i < E_; ++i) acc += sAlpha[i] * sR[i][d];
    ent_rep[(size_t)b * MD_ + d] = tanhf(acc);
  }
}

// ---------------------------------------------------------------------------
// Category + subcategory: gather -> [50]x[50,400] matvec -> tanh
// ---------------------------------------------------------------------------
__global__ __launch_bounds__(256) void catsub_kernel(
    const int* __restrict__ cat_idx, const int* __restrict__ sub_idx,
    const float* __restrict__ emb_cat, const float* __restrict__ fc1_w, const float* __restrict__ fc1_b,
    const float* __restrict__ emb_sub, const float* __restrict__ fc2_w, const float* __restrict__ fc2_b,
    float* __restrict__ cat_rep, float* __restrict__ sub_rep)
{
  int idx = blockIdx.x * 256 + threadIdx.x;
  const int total = B_ * MD_;
  if (idx < total) {
    const int b = idx / MD_, d = idx - (idx / MD_) * MD_;
    const float* row = emb_cat + (size_t)cat_idx[b] * CD_;
    float acc = fc1_b[d];
    #pragma unroll
    for (int k = 0; k < CD_; ++k) acc += row[k] * fc1_w[k * MD_ + d];
    cat_rep[idx] = tanhf(acc);
  } else {
    idx -= total;
    if (idx < total) {
      const int b = idx / MD_, d = idx - (idx / MD_) * MD_;
      const float* row = emb_sub + (size_t)sub_idx[b] * SD_;
      float acc = fc2_b[d];
      #pragma unroll
      for (int k = 0; k < SD_; ++k) acc += row[k] * fc2_w[k * MD_ + d];
      sub_rep[idx] = tanhf(acc);
    }
  }
}

// ---------------------------------------------------------------------------
// Final fusion: additive attention over the 4 views. One block per b.
// ---------------------------------------------------------------------------
__global__ __launch_bounds__(256) void fuse_kernel(
    const float* __restrict__ word_rep, const float* __restrict__ ent_rep,
    const float* __restrict__ cat_rep, const float* __restrict__ sub_rep,
    const float* __restrict__ na_w, const float* __restrict__ na_b, const float* __restrict__ na_q,
    float* __restrict__ out)                           // [B, MD]
{
  __shared__ float sViews[4][MD_];  // 6.4 KB
  __shared__ float sSc[4];
  __shared__ float sAlpha[4];
  const int b = blockIdx.x, tid = threadIdx.x;
  for (int d = tid; d < MD_; d += 256) {
    sViews[0][d] = word_rep[(size_t)b * MD_ + d];
    sViews[1][d] = ent_rep[(size_t)b * MD_ + d];
    sViews[2][d] = cat_rep[(size_t)b * MD_ + d];
    sViews[3][d] = sub_rep[(size_t)b * MD_ + d];
  }
  if (tid < 4) sSc[tid] = 0.f;
  __syncthreads();
  for (int id = tid; id < 4 * QD_; id += 256) {
    const int v = id / QD_, q = id - (id / QD_) * QD_;
    float acc = na_b[q];
    #pragma unroll 4
    for (int d = 0; d < MD_; ++d) acc += sViews[v][d] * na_w[d * QD_ + q];
    atomicAdd(&sSc[v], tanhf(acc) * na_q[q]);
  }
  __syncthreads();
  if (tid == 0) {
    float mx = -1e30f;
    for (int v = 0; v < 4; ++v) mx = fmaxf(mx, sSc[v]);
    float sum = 0.f;
    for (int v = 0; v < 4; ++v) { float e = __expf(sSc[v] - mx); sAlpha[v] = e; sum += e; }
    const float inv = 1.f / sum;
    for (int v = 0; v < 4; ++v) sAlpha[v] *= inv;
  }
  __syncthreads();
  for (int d = tid; d < MD_; d += 256) {
    const float acc = sAlpha[0] * sViews[0][d] + sAlpha[1] * sViews[1][d] +
                      sAlpha[2] * sViews[2][d] + sAlpha[3] * sViews[3][d];
    out[(size_t)b * MD_ + d] = tanhf(acc);
  }
}

// ---------------------------------------------------------------------------
extern "C" void kernel_launch(void* const* d_in, const int* in_sizes, int n_in,
                              void* d_out, int out_size, void* d_ws, size_t ws_size,
                              hipStream_t stream) {
  const float* X        = (const float*)d_in[0];
  const float* Ein      = (const float*)d_in[1];
  const int*   cat_idx  = (const int*)d_in[2];
  const int*   sub_idx  = (const int*)d_in[3];
  const float* emb_cat  = (const float*)d_in[4];
  const float* fc1_w    = (const float*)d_in[5];
  const float* fc1_b    = (const float*)d_in[6];
  const float* emb_sub  = (const float*)d_in[7];
  const float* fc2_w    = (const float*)d_in[8];
  const float* fc2_b    = (const float*)d_in[9];
  const float* wq       = (const float*)d_in[10];
  const float* bq       = (const float*)d_in[11];
  const float* wk       = (const float*)d_in[12];
  const float* bk       = (const float*)d_in[13];
  const float* wv       = (const float*)d_in[14];
  const float* bv       = (const float*)d_in[15];
  const float* ln_g     = (const float*)d_in[16];
  const float* ln_b     = (const float*)d_in[17];
  const float* wa_w     = (const float*)d_in[18];
  const float* wa_b     = (const float*)d_in[19];
  const float* wa_q     = (const float*)d_in[20];
  const float* fc3_w    = (const float*)d_in[21];
  const float* fc3_b    = (const float*)d_in[22];
  const float* gcn_A    = (const float*)d_in[23];
  const float* gcn_w    = (const float*)d_in[24];
  const float* gcn_b    = (const float*)d_in[25];
  const float* ea_w     = (const float*)d_in[26];
  const float* ea_b     = (const float*)d_in[27];
  const float* ea_q     = (const float*)d_in[28];
  const float* na_w     = (const float*)d_in[29];
  const float* na_b     = (const float*)d_in[30];
  const float* na_q     = (const float*)d_in[31];

  float* out = (float*)d_out;
  const size_t BM = (size_t)B_ * MD_;
  float* word_rep = (float*)d_ws;
  float* ent_rep  = word_rep + BM;
  float* cat_rep  = ent_rep + BM;
  float* sub_rep  = cat_rep + BM;

  word_branch_kernel<<<B_, 256, 0, stream>>>(X, wq, bq, wk, bk, wv, bv,
                                             ln_g, ln_b, wa_w, wa_b, wa_q, word_rep);
  entity_branch_kernel<<<B_, 256, 0, stream>>>(Ein, fc3_w, fc3_b, gcn_A, gcn_w, gcn_b,
                                               ln_g, ln_b, ea_w, ea_b, ea_q, ent_rep);
  catsub_kernel<<<(2 * B_ * MD_) / 256, 256, 0, stream>>>(cat_idx, sub_idx,
                                                          emb_cat, fc1_w, fc1_b,
                                                          emb_sub, fc2_w, fc2_b,
                                                          cat_rep, sub_rep);
  fuse_kernel<<<B_, 256, 0, stream>>>(word_rep, ent_rep, cat_rep, sub_rep,
                                      na_w, na_b, na_q, out);
}

// Round 2
// 2524.924 us; speedup vs baseline: 8.4326x; 8.4326x over previous
//
#include <hip/hip_runtime.h>
#include <hip/hip_bf16.h>
#include <math.h>

#define B_  4096
#define L_  30
#define WD_ 300
#define H_  20
#define AD_ 20
#define MD_ 400
#define E_  10
#define ED_ 100
#define QD_ 200
#define CD_ 50
#define SD_ 50

typedef unsigned short ushort_t;
typedef __attribute__((ext_vector_type(8))) short bf16x8_t;
typedef __attribute__((ext_vector_type(4))) float f32x4_t;

// strides
#define SX_STR   328      // bf16 elems per row of staged X (320 + 8 pad)
#define QKV_STR  1208     // bf16 elems per row of QKV (1200 + 8 pad)
#define OUTB_STR 424      // bf16 elems per row of LN-out bf16 (416 + 8 pad)
#define WT_K     320      // K-extent of Wqkv_t (300 padded to 320)
#define WAT_K    416      // K-extent of Wa_t (400 padded to 416)

__device__ __forceinline__ ushort_t f2bf(float f) {
  unsigned u = __builtin_bit_cast(unsigned, f);
  unsigned r = (u + 0x7fffu + ((u >> 16) & 1u)) >> 16;
  return (ushort_t)r;
}
__device__ __forceinline__ float bfbits_lo(unsigned packed) {   // low ushort -> float
  return __builtin_bit_cast(float, packed << 16);
}
__device__ __forceinline__ float bfbits_hi(unsigned packed) {   // high ushort -> float
  return __builtin_bit_cast(float, packed & 0xffff0000u);
}
__device__ __forceinline__ float bf2f(ushort_t h) {
  return __builtin_bit_cast(float, ((unsigned)h) << 16);
}

__device__ __forceinline__ float wave_reduce_sum(float v) {
  #pragma unroll
  for (int off = 32; off > 0; off >>= 1) v += __shfl_xor(v, off);
  return v;
}

// ---------------------------------------------------------------------------
// Weight prep: Wqkv_t bf16 [1200][320] (n-major, K contiguous, zero-padded)
//              Wa_t   bf16 [208][416]
// ---------------------------------------------------------------------------
__global__ __launch_bounds__(256) void prep_weights(
    const float* __restrict__ wq, const float* __restrict__ wk, const float* __restrict__ wv,
    const float* __restrict__ wa_w,
    ushort_t* __restrict__ Wt, ushort_t* __restrict__ Wat)
{
  int idx = blockIdx.x * 256 + threadIdx.x;
  const int n_qkv = 1200 * WT_K;
  if (idx < n_qkv) {
    const int n = idx / WT_K, k = idx - n * WT_K;
    float v = 0.f;
    if (k < WD_) {
      const float* w = (n < 400) ? wq : (n < 800) ? wk : wv;
      const int c = (n < 400) ? n : (n < 800) ? n - 400 : n - 800;
      v = w[k * MD_ + c];
    }
    Wt[idx] = f2bf(v);
  } else {
    idx -= n_qkv;
    if (idx < 208 * WAT_K) {
      const int q = idx / WAT_K, d = idx - q * WAT_K;
      float v = 0.f;
      if (q < QD_ && d < MD_) v = wa_w[d * QD_ + q];
      Wat[idx] = f2bf(v);
    }
  }
}

// ---------------------------------------------------------------------------
// Word branch, MFMA version. One block (512 thr, 8 waves) per news item.
// LDS ~146.5 KB -> 1 block/CU, 2 waves/SIMD.
// ---------------------------------------------------------------------------
__global__ __launch_bounds__(512) void word_branch_kernel(
    const float* __restrict__ X,                       // [B, L, WD]
    const ushort_t* __restrict__ Wt,                   // [1200][320] bf16
    const ushort_t* __restrict__ Wat,                  // [208][416] bf16
    const float* __restrict__ bq, const float* __restrict__ bk, const float* __restrict__ bv,
    const float* __restrict__ ln_g, const float* __restrict__ ln_b,
    const float* __restrict__ wa_b, const float* __restrict__ wa_q,
    float* __restrict__ word_rep)                      // [B, MD]
{
  __shared__ __align__(16) union {
    ushort_t x[32 * SX_STR];          // 20,992 B : staged X bf16
    float    s[5 * 30 * 32];          // 19,200 B : per-group scores
  } uA;
  __shared__ __align__(16) union {
    ushort_t qkv[32 * QKV_STR];       // 77,312 B : Q|K|V bf16
    ushort_t outb[32 * OUTB_STR];     // 27,136 B : LN output bf16
  } uB;
  __shared__ __align__(16) float sOut[30 * MD_];  // 48,000 B : MHA out / LN out f32
  __shared__ float sSc[32];
  __shared__ float sAlpha[32];

  const int b    = blockIdx.x;
  const int tid  = threadIdx.x;
  const int wave = tid >> 6;
  const int lane = tid & 63;
  const int lr   = lane & 15;   // row-in-tile (A) / col-in-tile (B, C)
  const int kg   = lane >> 4;   // k-group 0..3

  // ---- stage X -> bf16 LDS [32][320], zero pads ----
  const float* xb = X + (size_t)b * (L_ * WD_);
  for (int id = tid; id < 32 * 320; id += 512) {
    const int r = id / 320, c = id - (id / 320) * 320;
    float v = (r < L_ && c < WD_) ? xb[r * WD_ + c] : 0.f;
    uA.x[r * SX_STR + c] = f2bf(v);
  }
  __syncthreads();

  // ---- QKV GEMM: [32,320] @ [320,1200] via mfma 16x16x32, tiles 2M x 75N ----
  for (int jt = wave; jt < 38; jt += 8) {
    const int nt0 = 2 * jt, nt1 = 2 * jt + 1;
    const bool has1 = (nt1 < 75);
    f32x4_t a00 = {0,0,0,0}, a10 = {0,0,0,0}, a01 = {0,0,0,0}, a11 = {0,0,0,0};
    for (int ks = 0; ks < 10; ++ks) {
      const int kb = ks * 32 + kg * 8;
      bf16x8_t af0 = *reinterpret_cast<const bf16x8_t*>(&uA.x[lr * SX_STR + kb]);
      bf16x8_t af1 = *reinterpret_cast<const bf16x8_t*>(&uA.x[(16 + lr) * SX_STR + kb]);
      bf16x8_t bf0 = *reinterpret_cast<const bf16x8_t*>(&Wt[(nt0 * 16 + lr) * WT_K + kb]);
      a00 = __builtin_amdgcn_mfma_f32_16x16x32_bf16(af0, bf0, a00, 0, 0, 0);
      a10 = __builtin_amdgcn_mfma_f32_16x16x32_bf16(af1, bf0, a10, 0, 0, 0);
      if (has1) {
        bf16x8_t bf1 = *reinterpret_cast<const bf16x8_t*>(&Wt[(nt1 * 16 + lr) * WT_K + kb]);
        a01 = __builtin_amdgcn_mfma_f32_16x16x32_bf16(af0, bf1, a01, 0, 0, 0);
        a11 = __builtin_amdgcn_mfma_f32_16x16x32_bf16(af1, bf1, a11, 0, 0, 0);
      }
    }
    // epilogue: add bias, store bf16 to sQKV. C layout: col=lane&15, row=(lane>>4)*4+i
    #pragma unroll
    for (int half = 0; half < 2; ++half) {
      const int nt = half ? nt1 : nt0;
      if (half && !has1) break;
      const int col = nt * 16 + lr;
      const float bias = (col < 400) ? bq[col] : (col < 800) ? bk[col - 400] : bv[col - 800];
      const f32x4_t am0 = half ? a01 : a00;
      const f32x4_t am1 = half ? a11 : a10;
      #pragma unroll
      for (int i = 0; i < 4; ++i) {
        uB.qkv[(kg * 4 + i) * QKV_STR + col]      = f2bf(am0[i] + bias);
        uB.qkv[(16 + kg * 4 + i) * QKV_STR + col] = f2bf(am1[i] + bias);
      }
    }
  }
  __syncthreads();   // QKV ready; sX dead (uA reused as scores from here)

  // ---- attention: 4 groups of 5 heads; scores -> softmax -> PV ----
  for (int g = 0; g < 4; ++g) {
    // scores[hh][l][m]
    for (int id = tid; id < 5 * 30 * 30; id += 512) {
      const int hh = id / 900, rem = id - hh * 900;
      const int l = rem / 30, m = rem - (rem / 30) * 30;
      const int h = g * 5 + hh;
      const ushort_t* qrow = &uB.qkv[l * QKV_STR + h * AD_];
      const ushort_t* krow = &uB.qkv[m * QKV_STR + 400 + h * AD_];
      float acc = 0.f;
      #pragma unroll
      for (int d = 0; d < AD_; d += 2) {
        const unsigned qa = *reinterpret_cast<const unsigned*>(qrow + d);
        const unsigned ka = *reinterpret_cast<const unsigned*>(krow + d);
        acc += bfbits_lo(qa) * bfbits_lo(ka) + bfbits_hi(qa) * bfbits_hi(ka);
      }
      uA.s[(hh * 30 + l) * 32 + m] = acc * 0.2236067977499790f;
    }
    __syncthreads();
    // softmax per row
    if (tid < 150) {
      float* row = &uA.s[tid * 32];
      float mx = -1e30f;
      #pragma unroll 6
      for (int m = 0; m < 30; ++m) mx = fmaxf(mx, row[m]);
      float sum = 0.f;
      #pragma unroll 6
      for (int m = 0; m < 30; ++m) { const float e = __expf(row[m] - mx); row[m] = e; sum += e; }
      const float inv = 1.f / sum;
      #pragma unroll 6
      for (int m = 0; m < 30; ++m) row[m] *= inv;
    }
    __syncthreads();
    // PV: out[l][h*20 + 2dp .. +1]
    for (int id = tid; id < 5 * 30 * 10; id += 512) {
      const int hh = id / 300, rem = id - hh * 300;
      const int l = rem / 10, dp = rem - (rem / 10) * 10;
      const int h = g * 5 + hh;
      const int colv = 800 + h * AD_ + dp * 2;
      const float* prow = &uA.s[(hh * 30 + l) * 32];
      float s0 = 0.f, s1 = 0.f;
      #pragma unroll 6
      for (int m = 0; m < 30; ++m) {
        const float p = prow[m];
        const unsigned vv = *reinterpret_cast<const unsigned*>(&uB.qkv[m * QKV_STR + colv]);
        s0 += p * bfbits_lo(vv);
        s1 += p * bfbits_hi(vv);
      }
      sOut[l * MD_ + h * AD_ + dp * 2]     = s0;
      sOut[l * MD_ + h * AD_ + dp * 2 + 1] = s1;
    }
    __syncthreads();
  }

  // ---- LayerNorm rows of sOut (in place) ----
  for (int r = wave; r < L_; r += 8) {
    float s = 0.f, s2 = 0.f;
    for (int d = lane; d < MD_; d += 64) { const float v = sOut[r * MD_ + d]; s += v; s2 += v * v; }
    s  = wave_reduce_sum(s);
    s2 = wave_reduce_sum(s2);
    const float mu  = s * (1.f / MD_);
    const float var = s2 * (1.f / MD_) - mu * mu;
    const float inv = rsqrtf(var + 1e-5f);
    for (int d = lane; d < MD_; d += 64)
      sOut[r * MD_ + d] = (sOut[r * MD_ + d] - mu) * inv * ln_g[d] + ln_b[d];
  }
  __syncthreads();

  // ---- build bf16 copy of LN output for MFMA; zero sSc ----
  for (int id = tid; id < 32 * WAT_K; id += 512) {
    const int r = id / WAT_K, c = id - (id / WAT_K) * WAT_K;
    uB.outb[r * OUTB_STR + c] = (r < L_ && c < MD_) ? f2bf(sOut[r * MD_ + c]) : (ushort_t)0;
  }
  if (tid < 32) sSc[tid] = 0.f;
  __syncthreads();

  // ---- additive attention scores via MFMA: [32,416] @ [416,208] ----
  for (int t = wave; t < 26; t += 8) {
    const int mt = t & 1, nt = t >> 1;
    f32x4_t acc = {0,0,0,0};
    for (int ks = 0; ks < 13; ++ks) {
      const int kb = ks * 32 + kg * 8;
      bf16x8_t af = *reinterpret_cast<const bf16x8_t*>(&uB.outb[(mt * 16 + lr) * OUTB_STR + kb]);
      bf16x8_t wf = *reinterpret_cast<const bf16x8_t*>(&Wat[(nt * 16 + lr) * WAT_K + kb]);
      acc = __builtin_amdgcn_mfma_f32_16x16x32_bf16(af, wf, acc, 0, 0, 0);
    }
    const int q = nt * 16 + lr;
    if (q < QD_) {
      const float bb = wa_b[q], qq = wa_q[q];
      #pragma unroll
      for (int i = 0; i < 4; ++i) {
        const int row = mt * 16 + kg * 4 + i;
        if (row < L_) atomicAdd(&sSc[row], tanhf(acc[i] + bb) * qq);
      }
    }
  }
  __syncthreads();

  // ---- softmax over 30 title positions ----
  if (tid == 0) {
    float mx = -1e30f;
    for (int l = 0; l < L_; ++l) mx = fmaxf(mx, sSc[l]);
    float sum = 0.f;
    for (int l = 0; l < L_; ++l) { const float e = __expf(sSc[l] - mx); sAlpha[l] = e; sum += e; }
    const float inv = 1.f / sum;
    for (int l = 0; l < L_; ++l) sAlpha[l] *= inv;
  }
  __syncthreads();

  // ---- weighted sum + tanh ----
  for (int d = tid; d < MD_; d += 512) {
    float acc = 0.f;
    #pragma unroll 6
    for (int l = 0; l < L_; ++l) acc += sAlpha[l] * sOut[l * MD_ + d];
    word_rep[(size_t)b * MD_ + d] = tanhf(acc);
  }
}

// ---------------------------------------------------------------------------
// Entity branch: fc3 -> GCN -> LayerNorm -> additive attn. One block per b.
// ---------------------------------------------------------------------------
__global__ __launch_bounds__(256) void entity_branch_kernel(
    const float* __restrict__ Ein,                     // [B, E, ED]
    const float* __restrict__ fc3_w, const float* __restrict__ fc3_b,
    const float* __restrict__ gcn_A, const float* __restrict__ gcn_w, const float* __restrict__ gcn_b,
    const float* __restrict__ ln_g, const float* __restrict__ ln_b,
    const float* __restrict__ ea_w, const float* __restrict__ ea_b, const float* __restrict__ ea_q,
    float* __restrict__ ent_rep)                       // [B, MD]
{
  __shared__ float sRaw[E_][ED_];
  __shared__ float sE[E_][ED_];
  __shared__ float sR[E_][MD_];
  __shared__ float sA[E_][E_];
  __shared__ float sSc[E_];
  __shared__ float sAlpha[E_];

  const int b   = blockIdx.x;
  const int tid = threadIdx.x;
  const float* eb = Ein + (size_t)b * (E_ * ED_);
  for (int i = tid; i < E_ * ED_; i += 256) sRaw[i / ED_][i % ED_] = eb[i];
  if (tid < E_ * E_) sA[tid / E_][tid % E_] = gcn_A[tid];
  __syncthreads();

  for (int id = tid; id < E_ * ED_; id += 256) {
    const int i = id / ED_, d = id - (id / ED_) * ED_;
    float acc = fc3_b[d];
    #pragma unroll 4
    for (int k = 0; k < ED_; ++k) acc += sRaw[i][k] * fc3_w[k * ED_ + d];
    sE[i][d] = tanhf(acc);
  }
  __syncthreads();
  for (int id = tid; id < E_ * ED_; id += 256) {
    const int i = id / ED_, d = id - (id / ED_) * ED_;
    float acc = 0.f;
    #pragma unroll
    for (int f = 0; f < E_; ++f) acc += sA[i][f] * sE[f][d];
    sRaw[i][d] = acc;
  }
  __syncthreads();
  for (int id = tid; id < E_ * MD_; id += 256) {
    const int i = id / MD_, d = id - (id / MD_) * MD_;
    float acc = gcn_b[d];
    #pragma unroll 4
    for (int k = 0; k < ED_; ++k) acc += sRaw[i][k] * gcn_w[k * MD_ + d];
    sR[i][d] = fmaxf(acc, 0.f);
  }
  __syncthreads();

  const int wave = tid >> 6, lane = tid & 63;
  for (int r = wave; r < E_; r += 4) {
    float s = 0.f, s2 = 0.f;
    for (int d = lane; d < MD_; d += 64) { const float v = sR[r][d]; s += v; s2 += v * v; }
    s  = wave_reduce_sum(s);
    s2 = wave_reduce_sum(s2);
    const float mu  = s * (1.f / MD_);
    const float var = s2 * (1.f / MD_) - mu * mu;
    const float inv = rsqrtf(var + 1e-5f);
    for (int d = lane; d < MD_; d += 64)
      sR[r][d] = (sR[r][d] - mu) * inv * ln_g[d] + ln_b[d];
  }
  if (tid < E_) sSc[tid] = 0.f;
  __syncthreads();

  for (int id = tid; id < E_ * QD_; id += 256) {
    const int i = id / QD_, q = id - (id / QD_) * QD_;
    float acc = ea_b[q];
    #pragma unroll 4
    for (int d = 0; d < MD_; ++d) acc += sR[i][d] * ea_w[d * QD_ + q];
    atomicAdd(&sSc[i], tanhf(acc) * ea_q[q]);
  }
  __syncthreads();
  if (tid == 0) {
    float mx = -1e30f;
    for (int i = 0; i < E_; ++i) mx = fmaxf(mx, sSc[i]);
    float sum = 0.f;
    for (int i = 0; i < E_; ++i) { const float e = __expf(sSc[i] - mx); sAlpha[i] = e; sum += e; }
    const float inv = 1.f / sum;
    for (int i = 0; i < E_; ++i) sAlpha[i] *= inv;
  }
  __syncthreads();
  for (int d = tid; d < MD_; d += 256) {
    float acc = 0.f;
    #pragma unroll
    for (int i = 0; i < E_; ++i) acc += sAlpha[i] * sR[i][d];
    ent_rep[(size_t)b * MD_ + d] = tanhf(acc);
  }
}

// ---------------------------------------------------------------------------
__global__ __launch_bounds__(256) void catsub_kernel(
    const int* __restrict__ cat_idx, const int* __restrict__ sub_idx,
    const float* __restrict__ emb_cat, const float* __restrict__ fc1_w, const float* __restrict__ fc1_b,
    const float* __restrict__ emb_sub, const float* __restrict__ fc2_w, const float* __restrict__ fc2_b,
    float* __restrict__ cat_rep, float* __restrict__ sub_rep)
{
  int idx = blockIdx.x * 256 + threadIdx.x;
  const int total = B_ * MD_;
  if (idx < total) {
    const int b = idx / MD_, d = idx - (idx / MD_) * MD_;
    const float* row = emb_cat + (size_t)cat_idx[b] * CD_;
    float acc = fc1_b[d];
    #pragma unroll
    for (int k = 0; k < CD_; ++k) acc += row[k] * fc1_w[k * MD_ + d];
    cat_rep[idx] = tanhf(acc);
  } else {
    idx -= total;
    if (idx < total) {
      const int b = idx / MD_, d = idx - (idx / MD_) * MD_;
      const float* row = emb_sub + (size_t)sub_idx[b] * SD_;
      float acc = fc2_b[d];
      #pragma unroll
      for (int k = 0; k < SD_; ++k) acc += row[k] * fc2_w[k * MD_ + d];
      sub_rep[idx] = tanhf(acc);
    }
  }
}

// ---------------------------------------------------------------------------
__global__ __launch_bounds__(256) void fuse_kernel(
    const float* __restrict__ word_rep, const float* __restrict__ ent_rep,
    const float* __restrict__ cat_rep, const float* __restrict__ sub_rep,
    const float* __restrict__ na_w, const float* __restrict__ na_b, const float* __restrict__ na_q,
    float* __restrict__ out)
{
  __shared__ float sViews[4][MD_];
  __shared__ float sSc[4];
  __shared__ float sAlpha[4];
  const int b = blockIdx.x, tid = threadIdx.x;
  for (int d = tid; d < MD_; d += 256) {
    sViews[0][d] = word_rep[(size_t)b * MD_ + d];
    sViews[1][d] = ent_rep[(size_t)b * MD_ + d];
    sViews[2][d] = cat_rep[(size_t)b * MD_ + d];
    sViews[3][d] = sub_rep[(size_t)b * MD_ + d];
  }
  if (tid < 4) sSc[tid] = 0.f;
  __syncthreads();
  for (int id = tid; id < 4 * QD_; id += 256) {
    const int v = id / QD_, q = id - (id / QD_) * QD_;
    float acc = na_b[q];
    #pragma unroll 4
    for (int d = 0; d < MD_; ++d) acc += sViews[v][d] * na_w[d * QD_ + q];
    atomicAdd(&sSc[v], tanhf(acc) * na_q[q]);
  }
  __syncthreads();
  if (tid == 0) {
    float mx = -1e30f;
    for (int v = 0; v < 4; ++v) mx = fmaxf(mx, sSc[v]);
    float sum = 0.f;
    for (int v = 0; v < 4; ++v) { const float e = __expf(sSc[v] - mx); sAlpha[v] = e; sum += e; }
    const float inv = 1.f / sum;
    for (int v = 0; v < 4; ++v) sAlpha[v] *= inv;
  }
  __syncthreads();
  for (int d = tid; d < MD_; d += 256) {
    const float acc = sAlpha[0] * sViews[0][d] + sAlpha[1] * sViews[1][d] +
                      sAlpha[2] * sViews[2][d] + sAlpha[3] * sViews[3][d];
    out[(size_t)b * MD_ + d] = tanhf(acc);
  }
}

// ---------------------------------------------------------------------------
extern "C" void kernel_launch(void* const* d_in, const int* in_sizes, int n_in,
                              void* d_out, int out_size, void* d_ws, size_t ws_size,
                              hipStream_t stream) {
  const float* X        = (const float*)d_in[0];
  const float* Ein      = (const float*)d_in[1];
  const int*   cat_idx  = (const int*)d_in[2];
  const int*   sub_idx  = (const int*)d_in[3];
  const float* emb_cat  = (const float*)d_in[4];
  const float* fc1_w    = (const float*)d_in[5];
  const float* fc1_b    = (const float*)d_in[6];
  const float* emb_sub  = (const float*)d_in[7];
  const float* fc2_w    = (const float*)d_in[8];
  const float* fc2_b    = (const float*)d_in[9];
  const float* wq       = (const float*)d_in[10];
  const float* bq       = (const float*)d_in[11];
  const float* wk       = (const float*)d_in[12];
  const float* bk       = (const float*)d_in[13];
  const float* wv       = (const float*)d_in[14];
  const float* bv       = (const float*)d_in[15];
  const float* ln_g     = (const float*)d_in[16];
  const float* ln_b     = (const float*)d_in[17];
  const float* wa_w     = (const float*)d_in[18];
  const float* wa_b     = (const float*)d_in[19];
  const float* wa_q     = (const float*)d_in[20];
  const float* fc3_w    = (const float*)d_in[21];
  const float* fc3_b    = (const float*)d_in[22];
  const float* gcn_A    = (const float*)d_in[23];
  const float* gcn_w    = (const float*)d_in[24];
  const float* gcn_b    = (const float*)d_in[25];
  const float* ea_w     = (const float*)d_in[26];
  const float* ea_b     = (const float*)d_in[27];
  const float* ea_q     = (const float*)d_in[28];
  const float* na_w     = (const float*)d_in[29];
  const float* na_b     = (const float*)d_in[30];
  const float* na_q     = (const float*)d_in[31];

  float* out = (float*)d_out;
  const size_t BM = (size_t)B_ * MD_;
  float* word_rep = (float*)d_ws;
  float* ent_rep  = word_rep + BM;
  float* cat_rep  = ent_rep + BM;
  float* sub_rep  = cat_rep + BM;
  ushort_t* Wt  = (ushort_t*)(sub_rep + BM);            // [1200][320] bf16
  ushort_t* Wat = Wt + 1200 * WT_K;                     // [208][416] bf16

  {
    const int total = 1200 * WT_K + 208 * WAT_K;
    prep_weights<<<(total + 255) / 256, 256, 0, stream>>>(wq, wk, wv, wa_w, Wt, Wat);
  }
  word_branch_kernel<<<B_, 512, 0, stream>>>(X, Wt, Wat, bq, bk, bv,
                                             ln_g, ln_b, wa_b, wa_q, word_rep);
  entity_branch_kernel<<<B_, 256, 0, stream>>>(Ein, fc3_w, fc3_b, gcn_A, gcn_w, gcn_b,
                                               ln_g, ln_b, ea_w, ea_b, ea_q, ent_rep);
  catsub_kernel<<<(2 * B_ * MD_) / 256, 256, 0, stream>>>(cat_idx, sub_idx,
                                                          emb_cat, fc1_w, fc1_b,
                                                          emb_sub, fc2_w, fc2_b,
                                                          cat_rep, sub_rep);
  fuse_kernel<<<B_, 256, 0, stream>>>(word_rep, ent_rep, cat_rep, sub_rep,
                                      na_w, na_b, na_q, out);
}

// Round 4
// 1500.423 us; speedup vs baseline: 14.1905x; 1.6828x over previous
//
#include <hip/hip_runtime.h>
#include <hip/hip_bf16.h>
#include <math.h>

#define B_  4096
#define L_  30
#define WD_ 300
#define H_  20
#define AD_ 20
#define MD_ 400
#define E_  10
#define ED_ 100
#define QD_ 200
#define CD_ 50
#define SD_ 50

typedef unsigned short ushort_t;
typedef __attribute__((ext_vector_type(8))) short bf16x8_t;
typedef __attribute__((ext_vector_type(4))) float f32x4_t;

// strides (elements)
#define SX_STR   328      // staged X row stride (320 + 8)
#define QKV_STR  1218     // QKV row stride
#define OUTB_STR 424      // LN-out bf16 row stride
#define SOUT_STR 401      // f32 MHA-out row stride (odd -> bank spread)
#define P_STR    33       // f32 P row stride
#define WT_K     320      // Wqkv K-extent (300 pad 320)
#define WAT_K    416      // Wa/Ea K-extent (400 pad 416)

// prep array sizes (elements per array)
#define N_WT    (1200 * WT_K)
#define N_WAT   (208 * WAT_K)
#define N_FC3T  (112 * 128)
#define N_GCNT  (400 * 128)
#define N_EAT   (208 * WAT_K)

union FragU {
  unsigned  u[4];
  short     s[8];
  bf16x8_t  h;
};

__device__ __forceinline__ ushort_t f2bf(float f) {
  unsigned u = __builtin_bit_cast(unsigned, f);
  unsigned r = (u + 0x7fffu + ((u >> 16) & 1u)) >> 16;
  return (ushort_t)r;
}
__device__ __forceinline__ float bf2f(ushort_t h) {
  return __builtin_bit_cast(float, ((unsigned)h) << 16);
}
__device__ __forceinline__ float wave_reduce_sum(float v) {
  #pragma unroll
  for (int off = 32; off > 0; off >>= 1) v += __shfl_xor(v, off);
  return v;
}
__device__ __forceinline__ void split2(float v, ushort_t* __restrict__ H,
                                       ushort_t* __restrict__ Lo, int idx) {
  const ushort_t h = f2bf(v);
  H[idx] = h;
  Lo[idx] = f2bf(v - bf2f(h));
}

// ---------------------------------------------------------------------------
// Weight prep: Wt single-bf16; Wa/fc3/gcn/ea as hi/lo bf16 pairs (≈f32).
// ---------------------------------------------------------------------------
__global__ __launch_bounds__(256) void prep_weights(
    const float* __restrict__ wq, const float* __restrict__ wk, const float* __restrict__ wv,
    const float* __restrict__ wa_w, const float* __restrict__ fc3_w,
    const float* __restrict__ gcn_w, const float* __restrict__ ea_w,
    ushort_t* __restrict__ Wt,
    ushort_t* __restrict__ WatH, ushort_t* __restrict__ WatL,
    ushort_t* __restrict__ fc3TH, ushort_t* __restrict__ fc3TL,
    ushort_t* __restrict__ gcnTH, ushort_t* __restrict__ gcnTL,
    ushort_t* __restrict__ eaTH, ushort_t* __restrict__ eaTL)
{
  int idx = blockIdx.x * 256 + threadIdx.x;
  if (idx < N_WT) {
    const int n = idx / WT_K, k = idx - n * WT_K;
    float v = 0.f;
    if (k < WD_) {
      const float* w = (n < 400) ? wq : (n < 800) ? wk : wv;
      const int c = (n < 400) ? n : (n < 800) ? n - 400 : n - 800;
      v = w[k * MD_ + c];
    }
    Wt[idx] = f2bf(v);
    return;
  }
  idx -= N_WT;
  if (idx < N_WAT) {
    const int q = idx / WAT_K, d = idx - q * WAT_K;
    const float v = (q < QD_ && d < MD_) ? wa_w[d * QD_ + q] : 0.f;
    split2(v, WatH, WatL, idx);
    return;
  }
  idx -= N_WAT;
  if (idx < N_FC3T) {
    const int n = idx / 128, k = idx - n * 128;
    const float v = (n < ED_ && k < ED_) ? fc3_w[k * ED_ + n] : 0.f;
    split2(v, fc3TH, fc3TL, idx);
    return;
  }
  idx -= N_FC3T;
  if (idx < N_GCNT) {
    const int n = idx / 128, k = idx - n * 128;
    const float v = (k < ED_) ? gcn_w[k * MD_ + n] : 0.f;
    split2(v, gcnTH, gcnTL, idx);
    return;
  }
  idx -= N_GCNT;
  if (idx < N_EAT) {
    const int q = idx / WAT_K, d = idx - q * WAT_K;
    const float v = (q < QD_ && d < MD_) ? ea_w[d * QD_ + q] : 0.f;
    split2(v, eaTH, eaTL, idx);
  }
}

// ---------------------------------------------------------------------------
// Word branch. One block (512 thr, 8 waves) per news item. LDS 160,120 B.
// ---------------------------------------------------------------------------
__global__ __launch_bounds__(512) void word_branch_kernel(
    const float* __restrict__ X,
    const ushort_t* __restrict__ Wt,
    const ushort_t* __restrict__ WatH, const ushort_t* __restrict__ WatL,
    const float* __restrict__ bq, const float* __restrict__ bk, const float* __restrict__ bv,
    const float* __restrict__ ln_g, const float* __restrict__ ln_b,
    const float* __restrict__ wa_b, const float* __restrict__ wa_q,
    float* __restrict__ word_rep)
{
  __shared__ __align__(16) union {
    ushort_t x[32 * SX_STR];               // 20,992 B staged X
    float    p[8 * 32 * P_STR];            // 33,792 B per-wave f32 P tiles
  } uA;
  __shared__ __align__(16) union {
    ushort_t qkv[32 * QKV_STR];            // 77,952 B
    struct { ushort_t h[32 * OUTB_STR], l[32 * OUTB_STR]; } o;  // 54,272 B
  } uB;
  __shared__ __align__(16) float sOut[30 * SOUT_STR];  // 48,120 B
  __shared__ float sSc[32];
  __shared__ float sAlpha[32];

  const int b    = blockIdx.x;
  const int tid  = threadIdx.x;
  const int wave = tid >> 6;
  const int lane = tid & 63;
  const int lr   = lane & 15;
  const int kg   = lane >> 4;

  // ---- stage X -> bf16 [32][320] (zero pads) ----
  const float* xb = X + (size_t)b * (L_ * WD_);
  {
    const int r = tid >> 4, c0 = tid & 15;
    #pragma unroll
    for (int k = 0; k < 20; ++k) {
      const int c = c0 + k * 16;
      const float v = (r < L_ && c < WD_) ? xb[r * WD_ + c] : 0.f;
      uA.x[r * SX_STR + c] = f2bf(v);
    }
  }
  if (tid < 32) sSc[tid] = 0.f;
  __syncthreads();

  // ---- QKV GEMM: [32,320] @ [320,1200], tiles 2M x 75N ----
  for (int jt = wave; jt < 38; jt += 8) {
    const int nt0 = 2 * jt, nt1 = 2 * jt + 1;
    const bool has1 = (nt1 < 75);
    f32x4_t a00 = {0,0,0,0}, a10 = {0,0,0,0}, a01 = {0,0,0,0}, a11 = {0,0,0,0};
    for (int ks = 0; ks < 10; ++ks) {
      const int kb = ks * 32 + kg * 8;
      bf16x8_t af0 = *reinterpret_cast<const bf16x8_t*>(&uA.x[lr * SX_STR + kb]);
      bf16x8_t af1 = *reinterpret_cast<const bf16x8_t*>(&uA.x[(16 + lr) * SX_STR + kb]);
      bf16x8_t bf0 = *reinterpret_cast<const bf16x8_t*>(&Wt[(nt0 * 16 + lr) * WT_K + kb]);
      a00 = __builtin_amdgcn_mfma_f32_16x16x32_bf16(af0, bf0, a00, 0, 0, 0);
      a10 = __builtin_amdgcn_mfma_f32_16x16x32_bf16(af1, bf0, a10, 0, 0, 0);
      if (has1) {
        bf16x8_t bf1 = *reinterpret_cast<const bf16x8_t*>(&Wt[(nt1 * 16 + lr) * WT_K + kb]);
        a01 = __builtin_amdgcn_mfma_f32_16x16x32_bf16(af0, bf1, a01, 0, 0, 0);
        a11 = __builtin_amdgcn_mfma_f32_16x16x32_bf16(af1, bf1, a11, 0, 0, 0);
      }
    }
    #pragma unroll
    for (int half = 0; half < 2; ++half) {
      if (half && !has1) break;
      const int nt = half ? nt1 : nt0;
      const int col = nt * 16 + lr;
      const float bias = (col < 400) ? bq[col] : (col < 800) ? bk[col - 400] : bv[col - 800];
      const f32x4_t am0 = half ? a01 : a00;
      const f32x4_t am1 = half ? a11 : a10;
      #pragma unroll
      for (int i = 0; i < 4; ++i) {
        uB.qkv[(kg * 4 + i) * QKV_STR + col]      = f2bf(am0[i] + bias);
        uB.qkv[(16 + kg * 4 + i) * QKV_STR + col] = f2bf(am1[i] + bias);
      }
    }
  }
  __syncthreads();   // QKV ready; uA.x dead -> uA.p live

  // ---- per-head MFMA attention: scores -> in-register softmax -> PV ----
  float* pw = &uA.p[wave * (32 * P_STR)];
  for (int h = wave; h < H_; h += 8) {
    const int hq = h * AD_, hk = 400 + h * AD_, hv = 800 + h * AD_;

    // A (Q) and B (K) fragments, K=20 zero-masked to 32
    bf16x8_t aq[2], bkf[2];
    #pragma unroll
    for (int t = 0; t < 2; ++t) {
      FragU fq, fk;
      fq.u[0]=fq.u[1]=fq.u[2]=fq.u[3]=0;
      fk.u[0]=fk.u[1]=fk.u[2]=fk.u[3]=0;
      if (kg < 3) {
        const ushort_t* pq = &uB.qkv[(t * 16 + lr) * QKV_STR + hq + kg * 8];
        const ushort_t* pk = &uB.qkv[(t * 16 + lr) * QKV_STR + hk + kg * 8];
        fq.u[0] = *(const unsigned*)(pq);     fq.u[1] = *(const unsigned*)(pq + 2);
        fk.u[0] = *(const unsigned*)(pk);     fk.u[1] = *(const unsigned*)(pk + 2);
        if (kg < 2) {
          fq.u[2] = *(const unsigned*)(pq + 4); fq.u[3] = *(const unsigned*)(pq + 6);
          fk.u[2] = *(const unsigned*)(pk + 4); fk.u[3] = *(const unsigned*)(pk + 6);
        }
      }
      aq[t] = fq.h; bkf[t] = fk.h;
    }
    f32x4_t c00 = {0,0,0,0}, c01 = {0,0,0,0}, c10 = {0,0,0,0}, c11 = {0,0,0,0};
    c00 = __builtin_amdgcn_mfma_f32_16x16x32_bf16(aq[0], bkf[0], c00, 0, 0, 0);
    c01 = __builtin_amdgcn_mfma_f32_16x16x32_bf16(aq[0], bkf[1], c01, 0, 0, 0);
    c10 = __builtin_amdgcn_mfma_f32_16x16x32_bf16(aq[1], bkf[0], c10, 0, 0, 0);
    c11 = __builtin_amdgcn_mfma_f32_16x16x32_bf16(aq[1], bkf[1], c11, 0, 0, 0);

    // in-register softmax over m; P stored f32 to per-wave LDS tile
    const float SCALE = 0.2236067977499790f;
    #pragma unroll
    for (int mt = 0; mt < 2; ++mt) {
      const f32x4_t v0f = mt ? c10 : c00;
      const f32x4_t v1f = mt ? c11 : c01;
      #pragma unroll
      for (int i = 0; i < 4; ++i) {
        const float v0 = v0f[i] * SCALE;
        const float v1 = (lr < 14) ? v1f[i] * SCALE : -1e30f;
        float mx = fmaxf(v0, v1);
        mx = fmaxf(mx, __shfl_xor(mx, 1));
        mx = fmaxf(mx, __shfl_xor(mx, 2));
        mx = fmaxf(mx, __shfl_xor(mx, 4));
        mx = fmaxf(mx, __shfl_xor(mx, 8));
        const float e0 = __expf(v0 - mx);
        const float e1 = (lr < 14) ? __expf(v1 - mx) : 0.f;
        float s = e0 + e1;
        s += __shfl_xor(s, 1);
        s += __shfl_xor(s, 2);
        s += __shfl_xor(s, 4);
        s += __shfl_xor(s, 8);
        const float inv = 1.f / s;
        const int row = mt * 16 + kg * 4 + i;
        pw[row * P_STR + lr]      = e0 * inv;
        pw[row * P_STR + 16 + lr] = e1 * inv;
      }
    }
    __asm__ volatile("s_waitcnt lgkmcnt(0)" ::: "memory");

    // PV: A = P split hi/lo (≈f32), B = V columns (bf16)
    bf16x8_t aph[2], apl[2];
    #pragma unroll
    for (int t = 0; t < 2; ++t) {
      FragU fh, fl;
      #pragma unroll
      for (int j = 0; j < 8; ++j) {
        const float p = pw[(t * 16 + lr) * P_STR + kg * 8 + j];
        const ushort_t hh = f2bf(p);
        fh.s[j] = (short)hh;
        fl.s[j] = (short)f2bf(p - bf2f(hh));
      }
      aph[t] = fh.h; apl[t] = fl.h;
    }
    bf16x8_t bvf[2];
    #pragma unroll
    for (int nt = 0; nt < 2; ++nt) {
      FragU f;
      const int d = nt * 16 + lr;
      if (d < AD_) {
        #pragma unroll
        for (int j = 0; j < 8; ++j)
          f.s[j] = (short)uB.qkv[(kg * 8 + j) * QKV_STR + hv + d];
      } else {
        f.u[0]=f.u[1]=f.u[2]=f.u[3]=0;
      }
      bvf[nt] = f.h;
    }
    f32x4_t o00 = {0,0,0,0}, o01 = {0,0,0,0}, o10 = {0,0,0,0}, o11 = {0,0,0,0};
    o00 = __builtin_amdgcn_mfma_f32_16x16x32_bf16(aph[0], bvf[0], o00, 0, 0, 0);
    o00 = __builtin_amdgcn_mfma_f32_16x16x32_bf16(apl[0], bvf[0], o00, 0, 0, 0);
    o01 = __builtin_amdgcn_mfma_f32_16x16x32_bf16(aph[0], bvf[1], o01, 0, 0, 0);
    o01 = __builtin_amdgcn_mfma_f32_16x16x32_bf16(apl[0], bvf[1], o01, 0, 0, 0);
    o10 = __builtin_amdgcn_mfma_f32_16x16x32_bf16(aph[1], bvf[0], o10, 0, 0, 0);
    o10 = __builtin_amdgcn_mfma_f32_16x16x32_bf16(apl[1], bvf[0], o10, 0, 0, 0);
    o11 = __builtin_amdgcn_mfma_f32_16x16x32_bf16(aph[1], bvf[1], o11, 0, 0, 0);
    o11 = __builtin_amdgcn_mfma_f32_16x16x32_bf16(apl[1], bvf[1], o11, 0, 0, 0);

    #pragma unroll
    for (int mt = 0; mt < 2; ++mt) {
      #pragma unroll
      for (int nt = 0; nt < 2; ++nt) {
        const f32x4_t o = mt ? (nt ? o11 : o10) : (nt ? o01 : o00);
        const int d = nt * 16 + lr;
        if (d < AD_) {
          #pragma unroll
          for (int i = 0; i < 4; ++i) {
            const int r = mt * 16 + kg * 4 + i;
            if (r < L_) sOut[r * SOUT_STR + h * AD_ + d] = o[i];
          }
        }
      }
    }
  }
  __syncthreads();

  // ---- LayerNorm rows ----
  for (int r = wave; r < L_; r += 8) {
    float s = 0.f, s2 = 0.f;
    for (int d = lane; d < MD_; d += 64) { const float v = sOut[r * SOUT_STR + d]; s += v; s2 += v * v; }
    s  = wave_reduce_sum(s);
    s2 = wave_reduce_sum(s2);
    const float mu  = s * (1.f / MD_);
    const float var = s2 * (1.f / MD_) - mu * mu;
    const float inv = rsqrtf(var + 1e-5f);
    for (int d = lane; d < MD_; d += 64)
      sOut[r * SOUT_STR + d] = (sOut[r * SOUT_STR + d] - mu) * inv * ln_g[d] + ln_b[d];
  }
  __syncthreads();

  // ---- hi/lo bf16 copy of LN output (uB.qkv dead -> uB.o) ----
  {
    const int r = tid >> 4, c0 = tid & 15;
    #pragma unroll
    for (int k = 0; k < 26; ++k) {
      const int c = c0 + k * 16;
      const float v = (r < L_ && c < MD_) ? sOut[r * SOUT_STR + c] : 0.f;
      const ushort_t hh = f2bf(v);
      uB.o.h[r * OUTB_STR + c] = hh;
      uB.o.l[r * OUTB_STR + c] = f2bf(v - bf2f(hh));
    }
  }
  __syncthreads();

  // ---- additive attention scores via 3-term hi/lo MFMA ----
  for (int t = wave; t < 26; t += 8) {
    const int mt = t & 1, nt = t >> 1;
    f32x4_t acc = {0,0,0,0};
    for (int ks = 0; ks < 13; ++ks) {
      const int kb = ks * 32 + kg * 8;
      bf16x8_t ah = *reinterpret_cast<const bf16x8_t*>(&uB.o.h[(mt * 16 + lr) * OUTB_STR + kb]);
      bf16x8_t al = *reinterpret_cast<const bf16x8_t*>(&uB.o.l[(mt * 16 + lr) * OUTB_STR + kb]);
      bf16x8_t wh = *reinterpret_cast<const bf16x8_t*>(&WatH[(nt * 16 + lr) * WAT_K + kb]);
      bf16x8_t wl = *reinterpret_cast<const bf16x8_t*>(&WatL[(nt * 16 + lr) * WAT_K + kb]);
      acc = __builtin_amdgcn_mfma_f32_16x16x32_bf16(ah, wh, acc, 0, 0, 0);
      acc = __builtin_amdgcn_mfma_f32_16x16x32_bf16(al, wh, acc, 0, 0, 0);
      acc = __builtin_amdgcn_mfma_f32_16x16x32_bf16(ah, wl, acc, 0, 0, 0);
    }
    const int q = nt * 16 + lr;
    if (q < QD_) {
      const float bb = wa_b[q], qq = wa_q[q];
      #pragma unroll
      for (int i = 0; i < 4; ++i) {
        const int row = mt * 16 + kg * 4 + i;
        if (row < L_) atomicAdd(&sSc[row], tanhf(acc[i] + bb) * qq);
      }
    }
  }
  __syncthreads();

  // ---- softmax over 30 positions (wave 0) ----
  if (wave == 0) {
    const float v = (lane < L_) ? sSc[lane] : -1e30f;
    float mx = v;
    #pragma unroll
    for (int off = 32; off > 0; off >>= 1) mx = fmaxf(mx, __shfl_xor(mx, off));
    const float e = (lane < L_) ? __expf(v - mx) : 0.f;
    float s = e;
    #pragma unroll
    for (int off = 32; off > 0; off >>= 1) s += __shfl_xor(s, off);
    if (lane < L_) sAlpha[lane] = e / s;
  }
  __syncthreads();

  for (int d = tid; d < MD_; d += 512) {
    float acc = 0.f;
    #pragma unroll 6
    for (int l = 0; l < L_; ++l) acc += sAlpha[l] * sOut[l * SOUT_STR + d];
    word_rep[(size_t)b * MD_ + d] = tanhf(acc);
  }
}

// ---------------------------------------------------------------------------
// Entity branch: hi/lo 3-term MFMA everywhere; g = A@e scalar f32.
// One block (256 thr, 4 waves) per news item. LDS ~74.5 KB -> 2 blocks/CU.
// ---------------------------------------------------------------------------
__global__ __launch_bounds__(256) void entity_branch_kernel(
    const float* __restrict__ Ein,
    const ushort_t* __restrict__ fc3TH, const ushort_t* __restrict__ fc3TL,
    const float* __restrict__ fc3_b,
    const float* __restrict__ gcn_A,
    const ushort_t* __restrict__ gcnTH, const ushort_t* __restrict__ gcnTL,
    const float* __restrict__ gcn_b,
    const float* __restrict__ ln_g, const float* __restrict__ ln_b,
    const ushort_t* __restrict__ eaTH, const ushort_t* __restrict__ eaTL,
    const float* __restrict__ ea_b, const float* __restrict__ ea_q,
    float* __restrict__ ent_rep)
{
  __shared__ __align__(16) ushort_t sEh[16 * 136], sEl[16 * 136];
  __shared__ __align__(16) float    eF[E_ * 104];          // e f32 [f][d]
  __shared__ __align__(16) ushort_t gH[16 * 136], gL[16 * 136];
  __shared__ __align__(16) float    sR[16 * SOUT_STR];
  __shared__ __align__(16) ushort_t oH[16 * OUTB_STR], oL[16 * OUTB_STR];
  __shared__ float sSc[16];
  __shared__ float sAlpha[16];

  const int b    = blockIdx.x;
  const int tid  = threadIdx.x;
  const int wave = tid >> 6;
  const int lane = tid & 63;
  const int lr   = lane & 15;
  const int kg   = lane >> 4;

  // stage E hi/lo -> [16][128] (pads zero); zero-init g tiles
  {
    const int r = tid >> 4, c0 = tid & 15;
    #pragma unroll
    for (int k = 0; k < 8; ++k) {
      const int c = c0 + k * 16;
      const float v = (r < E_ && c < ED_) ? Ein[(size_t)b * (E_ * ED_) + r * ED_ + c] : 0.f;
      const ushort_t hh = f2bf(v);
      sEh[r * 136 + c] = hh;
      sEl[r * 136 + c] = f2bf(v - bf2f(hh));
    }
  }
  for (int id = tid; id < 16 * 136; id += 256) { gH[id] = 0; gL[id] = 0; }
  if (tid < 16) sSc[tid] = 0.f;
  __syncthreads();

  // fc3 (3-term): e = tanh(E @ fc3_w + b) -> eF f32 [f][d]
  for (int nt = wave; nt < 7; nt += 4) {
    f32x4_t acc = {0,0,0,0};
    #pragma unroll
    for (int ks = 0; ks < 4; ++ks) {
      const int kb = ks * 32 + kg * 8;
      bf16x8_t ah = *reinterpret_cast<const bf16x8_t*>(&sEh[lr * 136 + kb]);
      bf16x8_t al = *reinterpret_cast<const bf16x8_t*>(&sEl[lr * 136 + kb]);
      bf16x8_t wh = *reinterpret_cast<const bf16x8_t*>(&fc3TH[(nt * 16 + lr) * 128 + kb]);
      bf16x8_t wl = *reinterpret_cast<const bf16x8_t*>(&fc3TL[(nt * 16 + lr) * 128 + kb]);
      acc = __builtin_amdgcn_mfma_f32_16x16x32_bf16(ah, wh, acc, 0, 0, 0);
      acc = __builtin_amdgcn_mfma_f32_16x16x32_bf16(al, wh, acc, 0, 0, 0);
      acc = __builtin_amdgcn_mfma_f32_16x16x32_bf16(ah, wl, acc, 0, 0, 0);
    }
    const int d = nt * 16 + lr;
    if (d < ED_) {
      const float bias = fc3_b[d];
      #pragma unroll
      for (int i = 0; i < 4; ++i) {
        const int r = kg * 4 + i;
        if (r < E_) eF[r * 104 + d] = tanhf(acc[i] + bias);
      }
    }
  }
  __syncthreads();

  // g = A @ e, scalar f32 (1000 MACs) -> hi/lo bf16 tiles
  for (int id = tid; id < E_ * ED_; id += 256) {
    const int i = id / ED_, d = id - (id / ED_) * ED_;
    float acc = 0.f;
    #pragma unroll
    for (int f = 0; f < E_; ++f) acc += gcn_A[i * E_ + f] * eF[f * 104 + d];
    const ushort_t hh = f2bf(acc);
    gH[i * 136 + d] = hh;
    gL[i * 136 + d] = f2bf(acc - bf2f(hh));
  }
  __syncthreads();

  // r = relu(g @ gcn_w + b) (3-term) -> sR f32
  for (int nt = wave; nt < 25; nt += 4) {
    f32x4_t acc = {0,0,0,0};
    #pragma unroll
    for (int ks = 0; ks < 4; ++ks) {
      const int kb = ks * 32 + kg * 8;
      bf16x8_t ah = *reinterpret_cast<const bf16x8_t*>(&gH[lr * 136 + kb]);
      bf16x8_t al = *reinterpret_cast<const bf16x8_t*>(&gL[lr * 136 + kb]);
      bf16x8_t wh = *reinterpret_cast<const bf16x8_t*>(&gcnTH[(nt * 16 + lr) * 128 + kb]);
      bf16x8_t wl = *reinterpret_cast<const bf16x8_t*>(&gcnTL[(nt * 16 + lr) * 128 + kb]);
      acc = __builtin_amdgcn_mfma_f32_16x16x32_bf16(ah, wh, acc, 0, 0, 0);
      acc = __builtin_amdgcn_mfma_f32_16x16x32_bf16(al, wh, acc, 0, 0, 0);
      acc = __builtin_amdgcn_mfma_f32_16x16x32_bf16(ah, wl, acc, 0, 0, 0);
    }
    const int d = nt * 16 + lr;
    const float bias = gcn_b[d];
    #pragma unroll
    for (int i = 0; i < 4; ++i) {
      const int r = kg * 4 + i;
      if (r < E_) sR[r * SOUT_STR + d] = fmaxf(acc[i] + bias, 0.f);
    }
  }
  __syncthreads();

  // LayerNorm rows
  for (int r = wave; r < E_; r += 4) {
    float s = 0.f, s2 = 0.f;
    for (int d = lane; d < MD_; d += 64) { const float v = sR[r * SOUT_STR + d]; s += v; s2 += v * v; }
    s  = wave_reduce_sum(s);
    s2 = wave_reduce_sum(s2);
    const float mu  = s * (1.f / MD_);
    const float var = s2 * (1.f / MD_) - mu * mu;
    const float inv = rsqrtf(var + 1e-5f);
    for (int d = lane; d < MD_; d += 64)
      sR[r * SOUT_STR + d] = (sR[r * SOUT_STR + d] - mu) * inv * ln_g[d] + ln_b[d];
  }
  __syncthreads();

  // hi/lo bf16 copy for additive MFMA
  {
    const int r = tid >> 4, c0 = tid & 15;
    #pragma unroll
    for (int k = 0; k < 26; ++k) {
      const int c = c0 + k * 16;
      const float v = (r < E_ && c < MD_) ? sR[r * SOUT_STR + c] : 0.f;
      const ushort_t hh = f2bf(v);
      oH[r * OUTB_STR + c] = hh;
      oL[r * OUTB_STR + c] = f2bf(v - bf2f(hh));
    }
  }
  __syncthreads();

  // additive attention scores (3-term): [16,416] @ [416,208]
  for (int nt = wave; nt < 13; nt += 4) {
    f32x4_t acc = {0,0,0,0};
    for (int ks = 0; ks < 13; ++ks) {
      const int kb = ks * 32 + kg * 8;
      bf16x8_t ah = *reinterpret_cast<const bf16x8_t*>(&oH[lr * OUTB_STR + kb]);
      bf16x8_t al = *reinterpret_cast<const bf16x8_t*>(&oL[lr * OUTB_STR + kb]);
      bf16x8_t wh = *reinterpret_cast<const bf16x8_t*>(&eaTH[(nt * 16 + lr) * WAT_K + kb]);
      bf16x8_t wl = *reinterpret_cast<const bf16x8_t*>(&eaTL[(nt * 16 + lr) * WAT_K + kb]);
      acc = __builtin_amdgcn_mfma_f32_16x16x32_bf16(ah, wh, acc, 0, 0, 0);
      acc = __builtin_amdgcn_mfma_f32_16x16x32_bf16(al, wh, acc, 0, 0, 0);
      acc = __builtin_amdgcn_mfma_f32_16x16x32_bf16(ah, wl, acc, 0, 0, 0);
    }
    const int q = nt * 16 + lr;
    if (q < QD_) {
      const float bb = ea_b[q], qq = ea_q[q];
      #pragma unroll
      for (int i = 0; i < 4; ++i) {
        const int r = kg * 4 + i;
        if (r < E_) atomicAdd(&sSc[r], tanhf(acc[i] + bb) * qq);
      }
    }
  }
  __syncthreads();

  if (wave == 0) {
    const float v = (lane < E_) ? sSc[lane] : -1e30f;
    float mx = v;
    #pragma unroll
    for (int off = 32; off > 0; off >>= 1) mx = fmaxf(mx, __shfl_xor(mx, off));
    const float e = (lane < E_) ? __expf(v - mx) : 0.f;
    float s = e;
    #pragma unroll
    for (int off = 32; off > 0; off >>= 1) s += __shfl_xor(s, off);
    if (lane < E_) sAlpha[lane] = e / s;
  }
  __syncthreads();

  for (int d = tid; d < MD_; d += 256) {
    float acc = 0.f;
    #pragma unroll
    for (int i = 0; i < E_; ++i) acc += sAlpha[i] * sR[i * SOUT_STR + d];
    ent_rep[(size_t)b * MD_ + d] = tanhf(acc);
  }
}

// ---------------------------------------------------------------------------
__global__ __launch_bounds__(256) void catsub_kernel(
    const int* __restrict__ cat_idx, const int* __restrict__ sub_idx,
    const float* __restrict__ emb_cat, const float* __restrict__ fc1_w, const float* __restrict__ fc1_b,
    const float* __restrict__ emb_sub, const float* __restrict__ fc2_w, const float* __restrict__ fc2_b,
    float* __restrict__ cat_rep, float* __restrict__ sub_rep)
{
  int idx = blockIdx.x * 256 + threadIdx.x;
  const int total = B_ * MD_;
  if (idx < total) {
    const int b = idx / MD_, d = idx - (idx / MD_) * MD_;
    const float* row = emb_cat + (size_t)cat_idx[b] * CD_;
    float acc = fc1_b[d];
    #pragma unroll
    for (int k = 0; k < CD_; ++k) acc += row[k] * fc1_w[k * MD_ + d];
    cat_rep[idx] = tanhf(acc);
  } else {
    idx -= total;
    if (idx < total) {
      const int b = idx / MD_, d = idx - (idx / MD_) * MD_;
      const float* row = emb_sub + (size_t)sub_idx[b] * SD_;
      float acc = fc2_b[d];
      #pragma unroll
      for (int k = 0; k < SD_; ++k) acc += row[k] * fc2_w[k * MD_ + d];
      sub_rep[idx] = tanhf(acc);
    }
  }
}

// ---------------------------------------------------------------------------
__global__ __launch_bounds__(256) void fuse_kernel(
    const float* __restrict__ word_rep, const float* __restrict__ ent_rep,
    const float* __restrict__ cat_rep, const float* __restrict__ sub_rep,
    const float* __restrict__ na_w, const float* __restrict__ na_b, const float* __restrict__ na_q,
    float* __restrict__ out)
{
  __shared__ float sViews[4][MD_];
  __shared__ float sSc[4];
  __shared__ float sAlpha[4];
  const int b = blockIdx.x, tid = threadIdx.x;
  for (int d = tid; d < MD_; d += 256) {
    sViews[0][d] = word_rep[(size_t)b * MD_ + d];
    sViews[1][d] = ent_rep[(size_t)b * MD_ + d];
    sViews[2][d] = cat_rep[(size_t)b * MD_ + d];
    sViews[3][d] = sub_rep[(size_t)b * MD_ + d];
  }
  if (tid < 4) sSc[tid] = 0.f;
  __syncthreads();
  for (int id = tid; id < 4 * QD_; id += 256) {
    const int v = id / QD_, q = id - (id / QD_) * QD_;
    float acc = na_b[q];
    #pragma unroll 4
    for (int d = 0; d < MD_; ++d) acc += sViews[v][d] * na_w[d * QD_ + q];
    atomicAdd(&sSc[v], tanhf(acc) * na_q[q]);
  }
  __syncthreads();
  if (tid == 0) {
    float mx = -1e30f;
    for (int v = 0; v < 4; ++v) mx = fmaxf(mx, sSc[v]);
    float sum = 0.f;
    for (int v = 0; v < 4; ++v) { const float e = __expf(sSc[v] - mx); sAlpha[v] = e; sum += e; }
    const float inv = 1.f / sum;
    for (int v = 0; v < 4; ++v) sAlpha[v] *= inv;
  }
  __syncthreads();
  for (int d = tid; d < MD_; d += 256) {
    const float acc = sAlpha[0] * sViews[0][d] + sAlpha[1] * sViews[1][d] +
                      sAlpha[2] * sViews[2][d] + sAlpha[3] * sViews[3][d];
    out[(size_t)b * MD_ + d] = tanhf(acc);
  }
}

// ---------------------------------------------------------------------------
extern "C" void kernel_launch(void* const* d_in, const int* in_sizes, int n_in,
                              void* d_out, int out_size, void* d_ws, size_t ws_size,
                              hipStream_t stream) {
  const float* X        = (const float*)d_in[0];
  const float* Ein      = (const float*)d_in[1];
  const int*   cat_idx  = (const int*)d_in[2];
  const int*   sub_idx  = (const int*)d_in[3];
  const float* emb_cat  = (const float*)d_in[4];
  const float* fc1_w    = (const float*)d_in[5];
  const float* fc1_b    = (const float*)d_in[6];
  const float* emb_sub  = (const float*)d_in[7];
  const float* fc2_w    = (const float*)d_in[8];
  const float* fc2_b    = (const float*)d_in[9];
  const float* wq       = (const float*)d_in[10];
  const float* bq       = (const float*)d_in[11];
  const float* wk       = (const float*)d_in[12];
  const float* bk       = (const float*)d_in[13];
  const float* wv       = (const float*)d_in[14];
  const float* bv       = (const float*)d_in[15];
  const float* ln_g     = (const float*)d_in[16];
  const float* ln_b     = (const float*)d_in[17];
  const float* wa_w     = (const float*)d_in[18];
  const float* wa_b     = (const float*)d_in[19];
  const float* wa_q     = (const float*)d_in[20];
  const float* fc3_w    = (const float*)d_in[21];
  const float* fc3_b    = (const float*)d_in[22];
  const float* gcn_A    = (const float*)d_in[23];
  const float* gcn_w    = (const float*)d_in[24];
  const float* gcn_b    = (const float*)d_in[25];
  const float* ea_w     = (const float*)d_in[26];
  const float* ea_b     = (const float*)d_in[27];
  const float* ea_q     = (const float*)d_in[28];
  const float* na_w     = (const float*)d_in[29];
  const float* na_b     = (const float*)d_in[30];
  const float* na_q     = (const float*)d_in[31];

  float* out = (float*)d_out;
  const size_t BM = (size_t)B_ * MD_;
  float* word_rep = (float*)d_ws;
  float* ent_rep  = word_rep + BM;
  float* cat_rep  = ent_rep + BM;
  float* sub_rep  = cat_rep + BM;
  ushort_t* Wt    = (ushort_t*)(sub_rep + BM);
  ushort_t* WatH  = Wt + N_WT;
  ushort_t* WatL  = WatH + N_WAT;
  ushort_t* fc3TH = WatL + N_WAT;
  ushort_t* fc3TL = fc3TH + N_FC3T;
  ushort_t* gcnTH = fc3TL + N_FC3T;
  ushort_t* gcnTL = gcnTH + N_GCNT;
  ushort_t* eaTH  = gcnTL + N_GCNT;
  ushort_t* eaTL  = eaTH + N_EAT;

  {
    const int total = N_WT + N_WAT + N_FC3T + N_GCNT + N_EAT;
    prep_weights<<<(total + 255) / 256, 256, 0, stream>>>(
        wq, wk, wv, wa_w, fc3_w, gcn_w, ea_w,
        Wt, WatH, WatL, fc3TH, fc3TL, gcnTH, gcnTL, eaTH, eaTL);
  }
  word_branch_kernel<<<B_, 512, 0, stream>>>(X, Wt, WatH, WatL, bq, bk, bv,
                                             ln_g, ln_b, wa_b, wa_q, word_rep);
  entity_branch_kernel<<<B_, 256, 0, stream>>>(Ein, fc3TH, fc3TL, fc3_b, gcn_A,
                                               gcnTH, gcnTL, gcn_b,
                                               ln_g, ln_b, eaTH, eaTL, ea_b, ea_q, ent_rep);
  catsub_kernel<<<(2 * B_ * MD_) / 256, 256, 0, stream>>>(cat_idx, sub_idx,
                                                          emb_cat, fc1_w, fc1_b,
                                                          emb_sub, fc2_w, fc2_b,
                                                          cat_rep, sub_rep);
  fuse_kernel<<<B_, 256, 0, stream>>>(word_rep, ent_rep, cat_rep, sub_rep,
                                      na_w, na_b, na_q, out);
}

// Round 5
// 1326.500 us; speedup vs baseline: 16.0510x; 1.1311x over previous
//
#include <hip/hip_runtime.h>
#include <hip/hip_bf16.h>
#include <math.h>

#define B_  4096
#define L_  30
#define WD_ 300
#define H_  20
#define AD_ 20
#define MD_ 400
#define E_  10
#define ED_ 100
#define QD_ 200
#define CD_ 50
#define SD_ 50

typedef unsigned short ushort_t;
typedef __attribute__((ext_vector_type(8))) short bf16x8_t;
typedef __attribute__((ext_vector_type(4))) float f32x4_t;

// strides (elements)
#define SX_STR   328      // staged X row stride (320 + 8)
#define QKV_STR  1218     // QKV row stride (30 rows only)
#define OUTB_STR 424      // LN-out bf16 row stride (32 rows, 30/31 zeroed)
#define SOUT_STR 401      // f32 MHA-out row stride (odd -> bank spread)
#define P_STR    40       // bf16 P row stride (per-wave tile 32 x 40)
#define WT_K     320      // Wqkv K-extent (300 pad 320)
#define WAT_K    416      // Wa/Ea K-extent (400 pad 416)

// prep array sizes (elements per array)
#define N_WT    (1200 * WT_K)
#define N_WAT   (208 * WAT_K)
#define N_FC3T  (112 * 128)
#define N_GCNT  (400 * 128)
#define N_EAT   (208 * WAT_K)

union FragU {
  unsigned  u[4];
  short     s[8];
  bf16x8_t  h;
};

__device__ __forceinline__ ushort_t f2bf(float f) {
  unsigned u = __builtin_bit_cast(unsigned, f);
  unsigned r = (u + 0x7fffu + ((u >> 16) & 1u)) >> 16;
  return (ushort_t)r;
}
__device__ __forceinline__ float bf2f(ushort_t h) {
  return __builtin_bit_cast(float, ((unsigned)h) << 16);
}
__device__ __forceinline__ float wave_reduce_sum(float v) {
  #pragma unroll
  for (int off = 32; off > 0; off >>= 1) v += __shfl_xor(v, off);
  return v;
}
__device__ __forceinline__ void split2(float v, ushort_t* __restrict__ H,
                                       ushort_t* __restrict__ Lo, int idx) {
  const ushort_t h = f2bf(v);
  H[idx] = h;
  Lo[idx] = f2bf(v - bf2f(h));
}

// ---------------------------------------------------------------------------
// Weight prep: Wt, Wat single-bf16; fc3/gcn/ea as hi/lo bf16 pairs (entity
// branch needs ~f32 — round-3 failure isolated the LN error amplification).
// ---------------------------------------------------------------------------
__global__ __launch_bounds__(256) void prep_weights(
    const float* __restrict__ wq, const float* __restrict__ wk, const float* __restrict__ wv,
    const float* __restrict__ wa_w, const float* __restrict__ fc3_w,
    const float* __restrict__ gcn_w, const float* __restrict__ ea_w,
    ushort_t* __restrict__ Wt, ushort_t* __restrict__ Wat,
    ushort_t* __restrict__ fc3TH, ushort_t* __restrict__ fc3TL,
    ushort_t* __restrict__ gcnTH, ushort_t* __restrict__ gcnTL,
    ushort_t* __restrict__ eaTH, ushort_t* __restrict__ eaTL)
{
  int idx = blockIdx.x * 256 + threadIdx.x;
  if (idx < N_WT) {
    const int n = idx / WT_K, k = idx - n * WT_K;
    float v = 0.f;
    if (k < WD_) {
      const float* w = (n < 400) ? wq : (n < 800) ? wk : wv;
      const int c = (n < 400) ? n : (n < 800) ? n - 400 : n - 800;
      v = w[k * MD_ + c];
    }
    Wt[idx] = f2bf(v);
    return;
  }
  idx -= N_WT;
  if (idx < N_WAT) {
    const int q = idx / WAT_K, d = idx - q * WAT_K;
    Wat[idx] = (q < QD_ && d < MD_) ? f2bf(wa_w[d * QD_ + q]) : (ushort_t)0;
    return;
  }
  idx -= N_WAT;
  if (idx < N_FC3T) {
    const int n = idx / 128, k = idx - n * 128;
    const float v = (n < ED_ && k < ED_) ? fc3_w[k * ED_ + n] : 0.f;
    split2(v, fc3TH, fc3TL, idx);
    return;
  }
  idx -= N_FC3T;
  if (idx < N_GCNT) {
    const int n = idx / 128, k = idx - n * 128;
    const float v = (k < ED_) ? gcn_w[k * MD_ + n] : 0.f;
    split2(v, gcnTH, gcnTL, idx);
    return;
  }
  idx -= N_GCNT;
  if (idx < N_EAT) {
    const int q = idx / WAT_K, d = idx - q * WAT_K;
    const float v = (q < QD_ && d < MD_) ? ea_w[d * QD_ + q] : 0.f;
    split2(v, eaTH, eaTL, idx);
  }
}

// ---------------------------------------------------------------------------
// Word branch. One block (1024 thr, 16 waves = 4/SIMD) per news item.
// LDS ~162.4 KB -> 1 block/CU but 2x the latency hiding of round 4.
// ---------------------------------------------------------------------------
__global__ __launch_bounds__(1024, 4) void word_branch_kernel(
    const float* __restrict__ X,
    const ushort_t* __restrict__ Wt, const ushort_t* __restrict__ Wat,
    const float* __restrict__ bq, const float* __restrict__ bk, const float* __restrict__ bv,
    const float* __restrict__ ln_g, const float* __restrict__ ln_b,
    const float* __restrict__ wa_b, const float* __restrict__ wa_q,
    float* __restrict__ word_rep)
{
  __shared__ __align__(16) union {
    ushort_t x[32 * SX_STR];               // 20,992 B staged X
    ushort_t p[16 * 32 * P_STR];           // 40,960 B per-wave bf16 P tiles
  } uA;
  __shared__ __align__(16) union {
    ushort_t qkv[30 * QKV_STR];            // 73,080 B (rows 0..29 only)
    ushort_t o[32 * OUTB_STR];             // 27,136 B LN-out bf16
  } uB;
  __shared__ __align__(16) float sOut[30 * SOUT_STR];  // 48,120 B
  __shared__ float sSc[32];
  __shared__ float sAlpha[32];

  const int b    = blockIdx.x;
  const int tid  = threadIdx.x;
  const int wave = tid >> 6;     // 0..15
  const int lane = tid & 63;
  const int lr   = lane & 15;
  const int kg   = lane >> 4;

  // ---- stage X -> bf16 [32][320] (zero pads) ----
  const float* xb = X + (size_t)b * (L_ * WD_);
  {
    const int r = tid >> 5;          // 0..31
    const int c0 = tid & 31;
    #pragma unroll
    for (int k = 0; k < 10; ++k) {
      const int c = c0 + k * 32;
      const float v = (r < L_ && c < WD_) ? xb[r * WD_ + c] : 0.f;
      uA.x[r * SX_STR + c] = f2bf(v);
    }
  }
  if (tid < 32) sSc[tid] = 0.f;
  __syncthreads();

  // ---- QKV GEMM: [32,320] @ [320,1200], tiles 2M x 75N ----
  for (int jt = wave; jt < 38; jt += 16) {
    const int nt0 = 2 * jt, nt1 = 2 * jt + 1;
    const bool has1 = (nt1 < 75);
    f32x4_t a00 = {0,0,0,0}, a10 = {0,0,0,0}, a01 = {0,0,0,0}, a11 = {0,0,0,0};
    for (int ks = 0; ks < 10; ++ks) {
      const int kb = ks * 32 + kg * 8;
      bf16x8_t af0 = *reinterpret_cast<const bf16x8_t*>(&uA.x[lr * SX_STR + kb]);
      bf16x8_t af1 = *reinterpret_cast<const bf16x8_t*>(&uA.x[(16 + lr) * SX_STR + kb]);
      bf16x8_t bf0 = *reinterpret_cast<const bf16x8_t*>(&Wt[(nt0 * 16 + lr) * WT_K + kb]);
      a00 = __builtin_amdgcn_mfma_f32_16x16x32_bf16(af0, bf0, a00, 0, 0, 0);
      a10 = __builtin_amdgcn_mfma_f32_16x16x32_bf16(af1, bf0, a10, 0, 0, 0);
      if (has1) {
        bf16x8_t bf1 = *reinterpret_cast<const bf16x8_t*>(&Wt[(nt1 * 16 + lr) * WT_K + kb]);
        a01 = __builtin_amdgcn_mfma_f32_16x16x32_bf16(af0, bf1, a01, 0, 0, 0);
        a11 = __builtin_amdgcn_mfma_f32_16x16x32_bf16(af1, bf1, a11, 0, 0, 0);
      }
    }
    #pragma unroll
    for (int half = 0; half < 2; ++half) {
      if (half && !has1) break;
      const int nt = half ? nt1 : nt0;
      const int col = nt * 16 + lr;
      const float bias = (col < 400) ? bq[col] : (col < 800) ? bk[col - 400] : bv[col - 800];
      const f32x4_t am0 = half ? a01 : a00;
      const f32x4_t am1 = half ? a11 : a10;
      #pragma unroll
      for (int i = 0; i < 4; ++i) {
        uB.qkv[(kg * 4 + i) * QKV_STR + col] = f2bf(am0[i] + bias);    // rows 0..15
        const int r2 = 16 + kg * 4 + i;
        if (r2 < L_) uB.qkv[r2 * QKV_STR + col] = f2bf(am1[i] + bias); // rows 16..29
      }
    }
  }
  __syncthreads();   // QKV ready; uA.x dead -> uA.p live

  // ---- per-head MFMA attention: scores -> in-register softmax -> PV ----
  ushort_t* pw = &uA.p[wave * (32 * P_STR)];
  for (int h = wave; h < H_; h += 16) {
    const int hq = h * AD_, hk = 400 + h * AD_, hv = 800 + h * AD_;

    // A (Q) and B (K) fragments, K=20 zero-masked to 32; rows>=30 zeroed
    bf16x8_t aq[2], bkf[2];
    #pragma unroll
    for (int t = 0; t < 2; ++t) {
      FragU fq, fk;
      fq.u[0]=fq.u[1]=fq.u[2]=fq.u[3]=0;
      fk.u[0]=fk.u[1]=fk.u[2]=fk.u[3]=0;
      const bool okrow = (t == 0) || (lr < 14);   // row t*16+lr <= 29
      if (okrow && kg < 3) {
        const ushort_t* pq = &uB.qkv[(t * 16 + lr) * QKV_STR + hq + kg * 8];
        const ushort_t* pk = &uB.qkv[(t * 16 + lr) * QKV_STR + hk + kg * 8];
        fq.u[0] = *(const unsigned*)(pq);     fq.u[1] = *(const unsigned*)(pq + 2);
        fk.u[0] = *(const unsigned*)(pk);     fk.u[1] = *(const unsigned*)(pk + 2);
        if (kg < 2) {
          fq.u[2] = *(const unsigned*)(pq + 4); fq.u[3] = *(const unsigned*)(pq + 6);
          fk.u[2] = *(const unsigned*)(pk + 4); fk.u[3] = *(const unsigned*)(pk + 6);
        }
      }
      aq[t] = fq.h; bkf[t] = fk.h;
    }
    f32x4_t c00 = {0,0,0,0}, c01 = {0,0,0,0}, c10 = {0,0,0,0}, c11 = {0,0,0,0};
    c00 = __builtin_amdgcn_mfma_f32_16x16x32_bf16(aq[0], bkf[0], c00, 0, 0, 0);
    c01 = __builtin_amdgcn_mfma_f32_16x16x32_bf16(aq[0], bkf[1], c01, 0, 0, 0);
    c10 = __builtin_amdgcn_mfma_f32_16x16x32_bf16(aq[1], bkf[0], c10, 0, 0, 0);
    c11 = __builtin_amdgcn_mfma_f32_16x16x32_bf16(aq[1], bkf[1], c11, 0, 0, 0);

    // in-register softmax over m; P stored bf16 to per-wave LDS tile
    const float SCALE = 0.2236067977499790f;
    #pragma unroll
    for (int mt = 0; mt < 2; ++mt) {
      const f32x4_t v0f = mt ? c10 : c00;
      const f32x4_t v1f = mt ? c11 : c01;
      #pragma unroll
      for (int i = 0; i < 4; ++i) {
        const float v0 = v0f[i] * SCALE;
        const float v1 = (lr < 14) ? v1f[i] * SCALE : -1e30f;
        float mx = fmaxf(v0, v1);
        mx = fmaxf(mx, __shfl_xor(mx, 1));
        mx = fmaxf(mx, __shfl_xor(mx, 2));
        mx = fmaxf(mx, __shfl_xor(mx, 4));
        mx = fmaxf(mx, __shfl_xor(mx, 8));
        const float e0 = __expf(v0 - mx);
        const float e1 = (lr < 14) ? __expf(v1 - mx) : 0.f;
        float s = e0 + e1;
        s += __shfl_xor(s, 1);
        s += __shfl_xor(s, 2);
        s += __shfl_xor(s, 4);
        s += __shfl_xor(s, 8);
        const float inv = 1.f / s;
        const int row = mt * 16 + kg * 4 + i;
        pw[row * P_STR + lr]      = f2bf(e0 * inv);
        pw[row * P_STR + 16 + lr] = f2bf(e1 * inv);
      }
    }
    __asm__ volatile("s_waitcnt lgkmcnt(0)" ::: "memory");

    // PV: A = P (K=32, cols 30/31 zero), B = V columns (rows>=30 zeroed)
    bf16x8_t ap[2];
    ap[0] = *reinterpret_cast<const bf16x8_t*>(&pw[lr * P_STR + kg * 8]);
    ap[1] = *reinterpret_cast<const bf16x8_t*>(&pw[(16 + lr) * P_STR + kg * 8]);
    bf16x8_t bvf[2];
    #pragma unroll
    for (int nt = 0; nt < 2; ++nt) {
      FragU f;
      const int d = nt * 16 + lr;
      if (d < AD_) {
        #pragma unroll
        for (int j = 0; j < 8; ++j) {
          const int rm = kg * 8 + j;
          f.s[j] = (rm < L_) ? (short)uB.qkv[rm * QKV_STR + hv + d] : (short)0;
        }
      } else {
        f.u[0]=f.u[1]=f.u[2]=f.u[3]=0;
      }
      bvf[nt] = f.h;
    }
    f32x4_t o00 = {0,0,0,0}, o01 = {0,0,0,0}, o10 = {0,0,0,0}, o11 = {0,0,0,0};
    o00 = __builtin_amdgcn_mfma_f32_16x16x32_bf16(ap[0], bvf[0], o00, 0, 0, 0);
    o01 = __builtin_amdgcn_mfma_f32_16x16x32_bf16(ap[0], bvf[1], o01, 0, 0, 0);
    o10 = __builtin_amdgcn_mfma_f32_16x16x32_bf16(ap[1], bvf[0], o10, 0, 0, 0);
    o11 = __builtin_amdgcn_mfma_f32_16x16x32_bf16(ap[1], bvf[1], o11, 0, 0, 0);

    #pragma unroll
    for (int mt = 0; mt < 2; ++mt) {
      #pragma unroll
      for (int nt = 0; nt < 2; ++nt) {
        const f32x4_t o = mt ? (nt ? o11 : o10) : (nt ? o01 : o00);
        const int d = nt * 16 + lr;
        if (d < AD_) {
          #pragma unroll
          for (int i = 0; i < 4; ++i) {
            const int r = mt * 16 + kg * 4 + i;
            if (r < L_) sOut[r * SOUT_STR + h * AD_ + d] = o[i];
          }
        }
      }
    }
  }
  __syncthreads();

  // ---- LayerNorm rows ----
  for (int r = wave; r < L_; r += 16) {
    float s = 0.f, s2 = 0.f;
    for (int d = lane; d < MD_; d += 64) { const float v = sOut[r * SOUT_STR + d]; s += v; s2 += v * v; }
    s  = wave_reduce_sum(s);
    s2 = wave_reduce_sum(s2);
    const float mu  = s * (1.f / MD_);
    const float var = s2 * (1.f / MD_) - mu * mu;
    const float inv = rsqrtf(var + 1e-5f);
    for (int d = lane; d < MD_; d += 64)
      sOut[r * SOUT_STR + d] = (sOut[r * SOUT_STR + d] - mu) * inv * ln_g[d] + ln_b[d];
  }
  __syncthreads();

  // ---- bf16 copy of LN output (uB.qkv dead -> uB.o; rows 30/31 zero) ----
  {
    const int r = tid >> 5;          // 0..31
    const int c0 = tid & 31;
    #pragma unroll
    for (int k = 0; k < 13; ++k) {
      const int c = c0 + k * 32;
      if (c < 416) {
        const float v = (r < L_ && c < MD_) ? sOut[r * SOUT_STR + c] : 0.f;
        uB.o[r * OUTB_STR + c] = f2bf(v);
      }
    }
  }
  __syncthreads();

  // ---- additive attention scores via MFMA: [32,416] @ [416,208] ----
  for (int t = wave; t < 26; t += 16) {
    const int mt = t & 1, nt = t >> 1;
    f32x4_t acc = {0,0,0,0};
    for (int ks = 0; ks < 13; ++ks) {
      const int kb = ks * 32 + kg * 8;
      bf16x8_t af = *reinterpret_cast<const bf16x8_t*>(&uB.o[(mt * 16 + lr) * OUTB_STR + kb]);
      bf16x8_t wf = *reinterpret_cast<const bf16x8_t*>(&Wat[(nt * 16 + lr) * WAT_K + kb]);
      acc = __builtin_amdgcn_mfma_f32_16x16x32_bf16(af, wf, acc, 0, 0, 0);
    }
    const int q = nt * 16 + lr;
    if (q < QD_) {
      const float bb = wa_b[q], qq = wa_q[q];
      #pragma unroll
      for (int i = 0; i < 4; ++i) {
        const int row = mt * 16 + kg * 4 + i;
        if (row < L_) atomicAdd(&sSc[row], tanhf(acc[i] + bb) * qq);
      }
    }
  }
  __syncthreads();

  // ---- softmax over 30 positions (wave 0) ----
  if (wave == 0) {
    const float v = (lane < L_) ? sSc[lane] : -1e30f;
    float mx = v;
    #pragma unroll
    for (int off = 32; off > 0; off >>= 1) mx = fmaxf(mx, __shfl_xor(mx, off));
    const float e = (lane < L_) ? __expf(v - mx) : 0.f;
    float s = e;
    #pragma unroll
    for (int off = 32; off > 0; off >>= 1) s += __shfl_xor(s, off);
    if (lane < L_) sAlpha[lane] = e / s;
  }
  __syncthreads();

  if (tid < MD_) {
    const int d = tid;
    float acc = 0.f;
    #pragma unroll 6
    for (int l = 0; l < L_; ++l) acc += sAlpha[l] * sOut[l * SOUT_STR + d];
    word_rep[(size_t)b * MD_ + d] = tanhf(acc);
  }
}

// ---------------------------------------------------------------------------
// Entity branch: hi/lo 3-term MFMA; g = A@e scalar f32.
// One block (512 thr, 8 waves) per news item. LDS ~74.5 KB -> 2 blocks/CU
// = 4 waves/SIMD.
// ---------------------------------------------------------------------------
__global__ __launch_bounds__(512, 4) void entity_branch_kernel(
    const float* __restrict__ Ein,
    const ushort_t* __restrict__ fc3TH, const ushort_t* __restrict__ fc3TL,
    const float* __restrict__ fc3_b,
    const float* __restrict__ gcn_A,
    const ushort_t* __restrict__ gcnTH, const ushort_t* __restrict__ gcnTL,
    const float* __restrict__ gcn_b,
    const float* __restrict__ ln_g, const float* __restrict__ ln_b,
    const ushort_t* __restrict__ eaTH, const ushort_t* __restrict__ eaTL,
    const float* __restrict__ ea_b, const float* __restrict__ ea_q,
    float* __restrict__ ent_rep)
{
  __shared__ __align__(16) ushort_t sEh[16 * 136], sEl[16 * 136];
  __shared__ __align__(16) float    eF[E_ * 104];          // e f32 [f][d]
  __shared__ __align__(16) ushort_t gH[16 * 136], gL[16 * 136];
  __shared__ __align__(16) float    sR[16 * SOUT_STR];
  __shared__ __align__(16) ushort_t oH[16 * OUTB_STR], oL[16 * OUTB_STR];
  __shared__ float sSc[16];
  __shared__ float sAlpha[16];

  const int b    = blockIdx.x;
  const int tid  = threadIdx.x;
  const int wave = tid >> 6;     // 0..7
  const int lane = tid & 63;
  const int lr   = lane & 15;
  const int kg   = lane >> 4;

  // stage E hi/lo -> [16][128] (pads zero); zero-init g tiles
  for (int id = tid; id < 16 * 128; id += 512) {
    const int r = id >> 7, c = id & 127;
    const float v = (r < E_ && c < ED_) ? Ein[(size_t)b * (E_ * ED_) + r * ED_ + c] : 0.f;
    const ushort_t hh = f2bf(v);
    sEh[r * 136 + c] = hh;
    sEl[r * 136 + c] = f2bf(v - bf2f(hh));
  }
  for (int id = tid; id < 16 * 136; id += 512) { gH[id] = 0; gL[id] = 0; }
  if (tid < 16) sSc[tid] = 0.f;
  __syncthreads();

  // fc3 (3-term): e = tanh(E @ fc3_w + b) -> eF f32 [f][d]
  for (int nt = wave; nt < 7; nt += 8) {
    f32x4_t acc = {0,0,0,0};
    #pragma unroll
    for (int ks = 0; ks < 4; ++ks) {
      const int kb = ks * 32 + kg * 8;
      bf16x8_t ah = *reinterpret_cast<const bf16x8_t*>(&sEh[lr * 136 + kb]);
      bf16x8_t al = *reinterpret_cast<const bf16x8_t*>(&sEl[lr * 136 + kb]);
      bf16x8_t wh = *reinterpret_cast<const bf16x8_t*>(&fc3TH[(nt * 16 + lr) * 128 + kb]);
      bf16x8_t wl = *reinterpret_cast<const bf16x8_t*>(&fc3TL[(nt * 16 + lr) * 128 + kb]);
      acc = __builtin_amdgcn_mfma_f32_16x16x32_bf16(ah, wh, acc, 0, 0, 0);
      acc = __builtin_amdgcn_mfma_f32_16x16x32_bf16(al, wh, acc, 0, 0, 0);
      acc = __builtin_amdgcn_mfma_f32_16x16x32_bf16(ah, wl, acc, 0, 0, 0);
    }
    const int d = nt * 16 + lr;
    if (d < ED_) {
      const float bias = fc3_b[d];
      #pragma unroll
      for (int i = 0; i < 4; ++i) {
        const int r = kg * 4 + i;
        if (r < E_) eF[r * 104 + d] = tanhf(acc[i] + bias);
      }
    }
  }
  __syncthreads();

  // g = A @ e, scalar f32 (1000 MACs) -> hi/lo bf16 tiles
  for (int id = tid; id < E_ * ED_; id += 512) {
    const int i = id / ED_, d = id - (id / ED_) * ED_;
    float acc = 0.f;
    #pragma unroll
    for (int f = 0; f < E_; ++f) acc += gcn_A[i * E_ + f] * eF[f * 104 + d];
    const ushort_t hh = f2bf(acc);
    gH[i * 136 + d] = hh;
    gL[i * 136 + d] = f2bf(acc - bf2f(hh));
  }
  __syncthreads();

  // r = relu(g @ gcn_w + b) (3-term) -> sR f32
  for (int nt = wave; nt < 25; nt += 8) {
    f32x4_t acc = {0,0,0,0};
    #pragma unroll
    for (int ks = 0; ks < 4; ++ks) {
      const int kb = ks * 32 + kg * 8;
      bf16x8_t ah = *reinterpret_cast<const bf16x8_t*>(&gH[lr * 136 + kb]);
      bf16x8_t al = *reinterpret_cast<const bf16x8_t*>(&gL[lr * 136 + kb]);
      bf16x8_t wh = *reinterpret_cast<const bf16x8_t*>(&gcnTH[(nt * 16 + lr) * 128 + kb]);
      bf16x8_t wl = *reinterpret_cast<const bf16x8_t*>(&gcnTL[(nt * 16 + lr) * 128 + kb]);
      acc = __builtin_amdgcn_mfma_f32_16x16x32_bf16(ah, wh, acc, 0, 0, 0);
      acc = __builtin_amdgcn_mfma_f32_16x16x32_bf16(al, wh, acc, 0, 0, 0);
      acc = __builtin_amdgcn_mfma_f32_16x16x32_bf16(ah, wl, acc, 0, 0, 0);
    }
    const int d = nt * 16 + lr;
    const float bias = gcn_b[d];
    #pragma unroll
    for (int i = 0; i < 4; ++i) {
      const int r = kg * 4 + i;
      if (r < E_) sR[r * SOUT_STR + d] = fmaxf(acc[i] + bias, 0.f);
    }
  }
  __syncthreads();

  // LayerNorm rows
  for (int r = wave; r < E_; r += 8) {
    float s = 0.f, s2 = 0.f;
    for (int d = lane; d < MD_; d += 64) { const float v = sR[r * SOUT_STR + d]; s += v; s2 += v * v; }
    s  = wave_reduce_sum(s);
    s2 = wave_reduce_sum(s2);
    const float mu  = s * (1.f / MD_);
    const float var = s2 * (1.f / MD_) - mu * mu;
    const float inv = rsqrtf(var + 1e-5f);
    for (int d = lane; d < MD_; d += 64)
      sR[r * SOUT_STR + d] = (sR[r * SOUT_STR + d] - mu) * inv * ln_g[d] + ln_b[d];
  }
  __syncthreads();

  // hi/lo bf16 copy for additive MFMA
  {
    const int r = tid >> 5;          // 0..15
    const int c0 = tid & 31;
    #pragma unroll
    for (int k = 0; k < 13; ++k) {
      const int c = c0 + k * 32;
      const float v = (r < E_ && c < MD_) ? sR[r * SOUT_STR + c] : 0.f;
      const ushort_t hh = f2bf(v);
      oH[r * OUTB_STR + c] = hh;
      oL[r * OUTB_STR + c] = f2bf(v - bf2f(hh));
    }
  }
  __syncthreads();

  // additive attention scores (3-term): [16,416] @ [416,208]
  for (int nt = wave; nt < 13; nt += 8) {
    f32x4_t acc = {0,0,0,0};
    for (int ks = 0; ks < 13; ++ks) {
      const int kb = ks * 32 + kg * 8;
      bf16x8_t ah = *reinterpret_cast<const bf16x8_t*>(&oH[lr * OUTB_STR + kb]);
      bf16x8_t al = *reinterpret_cast<const bf16x8_t*>(&oL[lr * OUTB_STR + kb]);
      bf16x8_t wh = *reinterpret_cast<const bf16x8_t*>(&eaTH[(nt * 16 + lr) * WAT_K + kb]);
      bf16x8_t wl = *reinterpret_cast<const bf16x8_t*>(&eaTL[(nt * 16 + lr) * WAT_K + kb]);
      acc = __builtin_amdgcn_mfma_f32_16x16x32_bf16(ah, wh, acc, 0, 0, 0);
      acc = __builtin_amdgcn_mfma_f32_16x16x32_bf16(al, wh, acc, 0, 0, 0);
      acc = __builtin_amdgcn_mfma_f32_16x16x32_bf16(ah, wl, acc, 0, 0, 0);
    }
    const int q = nt * 16 + lr;
    if (q < QD_) {
      const float bb = ea_b[q], qq = ea_q[q];
      #pragma unroll
      for (int i = 0; i < 4; ++i) {
        const int r = kg * 4 + i;
        if (r < E_) atomicAdd(&sSc[r], tanhf(acc[i] + bb) * qq);
      }
    }
  }
  __syncthreads();

  if (wave == 0) {
    const float v = (lane < E_) ? sSc[lane] : -1e30f;
    float mx = v;
    #pragma unroll
    for (int off = 32; off > 0; off >>= 1) mx = fmaxf(mx, __shfl_xor(mx, off));
    const float e = (lane < E_) ? __expf(v - mx) : 0.f;
    float s = e;
    #pragma unroll
    for (int off = 32; off > 0; off >>= 1) s += __shfl_xor(s, off);
    if (lane < E_) sAlpha[lane] = e / s;
  }
  __syncthreads();

  if (tid < MD_) {
    const int d = tid;
    float acc = 0.f;
    #pragma unroll
    for (int i = 0; i < E_; ++i) acc += sAlpha[i] * sR[i * SOUT_STR + d];
    ent_rep[(size_t)b * MD_ + d] = tanhf(acc);
  }
}

// ---------------------------------------------------------------------------
__global__ __launch_bounds__(256) void catsub_kernel(
    const int* __restrict__ cat_idx, const int* __restrict__ sub_idx,
    const float* __restrict__ emb_cat, const float* __restrict__ fc1_w, const float* __restrict__ fc1_b,
    const float* __restrict__ emb_sub, const float* __restrict__ fc2_w, const float* __restrict__ fc2_b,
    float* __restrict__ cat_rep, float* __restrict__ sub_rep)
{
  int idx = blockIdx.x * 256 + threadIdx.x;
  const int total = B_ * MD_;
  if (idx < total) {
    const int b = idx / MD_, d = idx - (idx / MD_) * MD_;
    const float* row = emb_cat + (size_t)cat_idx[b] * CD_;
    float acc = fc1_b[d];
    #pragma unroll
    for (int k = 0; k < CD_; ++k) acc += row[k] * fc1_w[k * MD_ + d];
    cat_rep[idx] = tanhf(acc);
  } else {
    idx -= total;
    if (idx < total) {
      const int b = idx / MD_, d = idx - (idx / MD_) * MD_;
      const float* row = emb_sub + (size_t)sub_idx[b] * SD_;
      float acc = fc2_b[d];
      #pragma unroll
      for (int k = 0; k < SD_; ++k) acc += row[k] * fc2_w[k * MD_ + d];
      sub_rep[idx] = tanhf(acc);
    }
  }
}

// ---------------------------------------------------------------------------
__global__ __launch_bounds__(256) void fuse_kernel(
    const float* __restrict__ word_rep, const float* __restrict__ ent_rep,
    const float* __restrict__ cat_rep, const float* __restrict__ sub_rep,
    const float* __restrict__ na_w, const float* __restrict__ na_b, const float* __restrict__ na_q,
    float* __restrict__ out)
{
  __shared__ float sViews[4][MD_];
  __shared__ float sSc[4];
  __shared__ float sAlpha[4];
  const int b = blockIdx.x, tid = threadIdx.x;
  for (int d = tid; d < MD_; d += 256) {
    sViews[0][d] = word_rep[(size_t)b * MD_ + d];
    sViews[1][d] = ent_rep[(size_t)b * MD_ + d];
    sViews[2][d] = cat_rep[(size_t)b * MD_ + d];
    sViews[3][d] = sub_rep[(size_t)b * MD_ + d];
  }
  if (tid < 4) sSc[tid] = 0.f;
  __syncthreads();
  for (int id = tid; id < 4 * QD_; id += 256) {
    const int v = id / QD_, q = id - (id / QD_) * QD_;
    float acc = na_b[q];
    #pragma unroll 4
    for (int d = 0; d < MD_; ++d) acc += sViews[v][d] * na_w[d * QD_ + q];
    atomicAdd(&sSc[v], tanhf(acc) * na_q[q]);
  }
  __syncthreads();
  if (tid == 0) {
    float mx = -1e30f;
    for (int v = 0; v < 4; ++v) mx = fmaxf(mx, sSc[v]);
    float sum = 0.f;
    for (int v = 0; v < 4; ++v) { const float e = __expf(sSc[v] - mx); sAlpha[v] = e; sum += e; }
    const float inv = 1.f / sum;
    for (int v = 0; v < 4; ++v) sAlpha[v] *= inv;
  }
  __syncthreads();
  for (int d = tid; d < MD_; d += 256) {
    const float acc = sAlpha[0] * sViews[0][d] + sAlpha[1] * sViews[1][d] +
                      sAlpha[2] * sViews[2][d] + sAlpha[3] * sViews[3][d];
    out[(size_t)b * MD_ + d] = tanhf(acc);
  }
}

// ---------------------------------------------------------------------------
extern "C" void kernel_launch(void* const* d_in, const int* in_sizes, int n_in,
                              void* d_out, int out_size, void* d_ws, size_t ws_size,
                              hipStream_t stream) {
  const float* X        = (const float*)d_in[0];
  const float* Ein      = (const float*)d_in[1];
  const int*   cat_idx  = (const int*)d_in[2];
  const int*   sub_idx  = (const int*)d_in[3];
  const float* emb_cat  = (const float*)d_in[4];
  const float* fc1_w    = (const float*)d_in[5];
  const float* fc1_b    = (const float*)d_in[6];
  const float* emb_sub  = (const float*)d_in[7];
  const float* fc2_w    = (const float*)d_in[8];
  const float* fc2_b    = (const float*)d_in[9];
  const float* wq       = (const float*)d_in[10];
  const float* bq       = (const float*)d_in[11];
  const float* wk       = (const float*)d_in[12];
  const float* bk       = (const float*)d_in[13];
  const float* wv       = (const float*)d_in[14];
  const float* bv       = (const float*)d_in[15];
  const float* ln_g     = (const float*)d_in[16];
  const float* ln_b     = (const float*)d_in[17];
  const float* wa_w     = (const float*)d_in[18];
  const float* wa_b     = (const float*)d_in[19];
  const float* wa_q     = (const float*)d_in[20];
  const float* fc3_w    = (const float*)d_in[21];
  const float* fc3_b    = (const float*)d_in[22];
  const float* gcn_A    = (const float*)d_in[23];
  const float* gcn_w    = (const float*)d_in[24];
  const float* gcn_b    = (const float*)d_in[25];
  const float* ea_w     = (const float*)d_in[26];
  const float* ea_b     = (const float*)d_in[27];
  const float* ea_q     = (const float*)d_in[28];
  const float* na_w     = (const float*)d_in[29];
  const float* na_b     = (const float*)d_in[30];
  const float* na_q     = (const float*)d_in[31];

  float* out = (float*)d_out;
  const size_t BM = (size_t)B_ * MD_;
  float* word_rep = (float*)d_ws;
  float* ent_rep  = word_rep + BM;
  float* cat_rep  = ent_rep + BM;
  float* sub_rep  = cat_rep + BM;
  ushort_t* Wt    = (ushort_t*)(sub_rep + BM);
  ushort_t* Wat   = Wt + N_WT;
  ushort_t* fc3TH = Wat + N_WAT;
  ushort_t* fc3TL = fc3TH + N_FC3T;
  ushort_t* gcnTH = fc3TL + N_FC3T;
  ushort_t* gcnTL = gcnTH + N_GCNT;
  ushort_t* eaTH  = gcnTL + N_GCNT;
  ushort_t* eaTL  = eaTH + N_EAT;

  {
    const int total = N_WT + N_WAT + N_FC3T + N_GCNT + N_EAT;
    prep_weights<<<(total + 255) / 256, 256, 0, stream>>>(
        wq, wk, wv, wa_w, fc3_w, gcn_w, ea_w,
        Wt, Wat, fc3TH, fc3TL, gcnTH, gcnTL, eaTH, eaTL);
  }
  word_branch_kernel<<<B_, 1024, 0, stream>>>(X, Wt, Wat, bq, bk, bv,
                                              ln_g, ln_b, wa_b, wa_q, word_rep);
  entity_branch_kernel<<<B_, 512, 0, stream>>>(Ein, fc3TH, fc3TL, fc3_b, gcn_A,
                                               gcnTH, gcnTL, gcn_b,
                                               ln_g, ln_b, eaTH, eaTL, ea_b, ea_q, ent_rep);
  catsub_kernel<<<(2 * B_ * MD_) / 256, 256, 0, stream>>>(cat_idx, sub_idx,
                                                          emb_cat, fc1_w, fc1_b,
                                                          emb_sub, fc2_w, fc2_b,
                                                          cat_rep, sub_rep);
  fuse_kernel<<<B_, 256, 0, stream>>>(word_rep, ent_rep, cat_rep, sub_rep,
                                      na_w, na_b, na_q, out);
}

// Round 7
// 1323.116 us; speedup vs baseline: 16.0921x; 1.0026x over previous
//
#include <hip/hip_runtime.h>
#include <hip/hip_bf16.h>
#include <math.h>

#define B_  4096
#define L_  30
#define WD_ 300
#define H_  20
#define AD_ 20
#define MD_ 400
#define E_  10
#define ED_ 100
#define QD_ 200
#define CD_ 50
#define SD_ 50

typedef unsigned short ushort_t;
typedef __attribute__((ext_vector_type(8))) short bf16x8_t;
typedef __attribute__((ext_vector_type(4))) float f32x4_t;

// strides (elements)
#define SX_STR   328      // staged X row stride (320 + 8)
#define QKV_STR  1218     // QKV row stride (30 rows only)
#define OUTB_STR 424      // LN-out bf16 row stride (32 rows, 30/31 zeroed)
#define SOUT_STR 401      // f32 MHA-out row stride (odd -> bank spread)
#define P_STR    40       // bf16 P row stride (per-wave tile 16 x 40)
#define WT_K     320      // Wqkv K-extent (300 pad 320)
#define WAT_K    416      // Wa/Ea K-extent (400 pad 416)

// prep array sizes (elements per array)
#define N_WT    (1200 * WT_K)
#define N_WAT   (208 * WAT_K)
#define N_FC3T  (112 * 128)
#define N_GCNT  (400 * 128)
#define N_EAT   (208 * WAT_K)

union FragU {
  unsigned  u[4];
  short     s[8];
  bf16x8_t  h;
};

__device__ __forceinline__ ushort_t f2bf(float f) {
  unsigned u = __builtin_bit_cast(unsigned, f);
  unsigned r = (u + 0x7fffu + ((u >> 16) & 1u)) >> 16;
  return (ushort_t)r;
}
__device__ __forceinline__ float bf2f(ushort_t h) {
  return __builtin_bit_cast(float, ((unsigned)h) << 16);
}
__device__ __forceinline__ float wave_reduce_sum(float v) {
  #pragma unroll
  for (int off = 32; off > 0; off >>= 1) v += __shfl_xor(v, off);
  return v;
}
__device__ __forceinline__ void split2(float v, ushort_t* __restrict__ H,
                                       ushort_t* __restrict__ Lo, int idx) {
  const ushort_t h = f2bf(v);
  H[idx] = h;
  Lo[idx] = f2bf(v - bf2f(h));
}

// ---------------------------------------------------------------------------
// Weight prep: Wt, Wat single-bf16; fc3/gcn/ea hi/lo pairs (entity branch
// REQUIRES 3-term everywhere incl. additive — single-term ea failed r6 at
// absmax 5e-2; the E=10 sharp softmax amplifies bf16 score noise).
// ---------------------------------------------------------------------------
__global__ __launch_bounds__(256) void prep_weights(
    const float* __restrict__ wq, const float* __restrict__ wk, const float* __restrict__ wv,
    const float* __restrict__ wa_w, const float* __restrict__ fc3_w,
    const float* __restrict__ gcn_w, const float* __restrict__ ea_w,
    ushort_t* __restrict__ Wt, ushort_t* __restrict__ Wat,
    ushort_t* __restrict__ fc3TH, ushort_t* __restrict__ fc3TL,
    ushort_t* __restrict__ gcnTH, ushort_t* __restrict__ gcnTL,
    ushort_t* __restrict__ eaTH, ushort_t* __restrict__ eaTL)
{
  int idx = blockIdx.x * 256 + threadIdx.x;
  if (idx < N_WT) {
    const int n = idx / WT_K, k = idx - n * WT_K;
    float v = 0.f;
    if (k < WD_) {
      const float* w = (n < 400) ? wq : (n < 800) ? wk : wv;
      const int c = (n < 400) ? n : (n < 800) ? n - 400 : n - 800;
      v = w[k * MD_ + c];
    }
    Wt[idx] = f2bf(v);
    return;
  }
  idx -= N_WT;
  if (idx < N_WAT) {
    const int q = idx / WAT_K, d = idx - q * WAT_K;
    Wat[idx] = (q < QD_ && d < MD_) ? f2bf(wa_w[d * QD_ + q]) : (ushort_t)0;
    return;
  }
  idx -= N_WAT;
  if (idx < N_FC3T) {
    const int n = idx / 128, k = idx - n * 128;
    const float v = (n < ED_ && k < ED_) ? fc3_w[k * ED_ + n] : 0.f;
    split2(v, fc3TH, fc3TL, idx);
    return;
  }
  idx -= N_FC3T;
  if (idx < N_GCNT) {
    const int n = idx / 128, k = idx - n * 128;
    const float v = (k < ED_) ? gcn_w[k * MD_ + n] : 0.f;
    split2(v, gcnTH, gcnTL, idx);
    return;
  }
  idx -= N_GCNT;
  if (idx < N_EAT) {
    const int q = idx / WAT_K, d = idx - q * WAT_K;
    const float v = (q < QD_ && d < MD_) ? ea_w[d * QD_ + q] : 0.f;
    split2(v, eaTH, eaTL, idx);
  }
}

// ---------------------------------------------------------------------------
// Word branch. 1024 thr (16 waves, 4/SIMD). LDS ~142 KB.
// QKV: 75 single-N-tile units (imb 1.07), all-K B-frag register prefetch.
// Attention: 40 (head, m-half) units (imb 1.2).
// ---------------------------------------------------------------------------
__global__ __launch_bounds__(1024, 4) void word_branch_kernel(
    const float* __restrict__ X,
    const ushort_t* __restrict__ Wt, const ushort_t* __restrict__ Wat,
    const float* __restrict__ bq, const float* __restrict__ bk, const float* __restrict__ bv,
    const float* __restrict__ ln_g, const float* __restrict__ ln_b,
    const float* __restrict__ wa_b, const float* __restrict__ wa_q,
    float* __restrict__ word_rep)
{
  __shared__ __align__(16) union {
    ushort_t x[32 * SX_STR];               // 20,992 B staged X
    ushort_t p[16 * 16 * P_STR];           // 20,480 B per-wave bf16 P half-tiles
  } uA;
  __shared__ __align__(16) union {
    ushort_t qkv[30 * QKV_STR];            // 73,080 B (rows 0..29)
    ushort_t o[32 * OUTB_STR];             // 27,136 B LN-out bf16
  } uB;
  __shared__ __align__(16) float sOut[30 * SOUT_STR];  // 48,120 B
  __shared__ float sSc[32];
  __shared__ float sAlpha[32];

  const int b    = blockIdx.x;
  const int tid  = threadIdx.x;
  const int wave = tid >> 6;     // 0..15
  const int lane = tid & 63;
  const int lr   = lane & 15;
  const int kg   = lane >> 4;

  // ---- stage X -> bf16 [32][320] (zero pads) ----
  const float* xb = X + (size_t)b * (L_ * WD_);
  {
    const int r = tid >> 5;          // 0..31
    const int c0 = tid & 31;
    #pragma unroll
    for (int k = 0; k < 10; ++k) {
      const int c = c0 + k * 32;
      const float v = (r < L_ && c < WD_) ? xb[r * WD_ + c] : 0.f;
      uA.x[r * SX_STR + c] = f2bf(v);
    }
  }
  if (tid < 32) sSc[tid] = 0.f;
  __syncthreads();

  // ---- QKV GEMM: [32,320] @ [320,1200], 75 N-tile units over 16 waves ----
  for (int nt = wave; nt < 75; nt += 16) {
    const ushort_t* wbase = &Wt[(nt * 16 + lr) * WT_K + kg * 8];
    bf16x8_t bfa[10];
    #pragma unroll
    for (int ks = 0; ks < 10; ++ks)
      bfa[ks] = *reinterpret_cast<const bf16x8_t*>(wbase + ks * 32);
    f32x4_t acc0 = {0,0,0,0}, acc1 = {0,0,0,0};
    #pragma unroll
    for (int ks = 0; ks < 10; ++ks) {
      const int kb = ks * 32 + kg * 8;
      bf16x8_t af0 = *reinterpret_cast<const bf16x8_t*>(&uA.x[lr * SX_STR + kb]);
      bf16x8_t af1 = *reinterpret_cast<const bf16x8_t*>(&uA.x[(16 + lr) * SX_STR + kb]);
      acc0 = __builtin_amdgcn_mfma_f32_16x16x32_bf16(af0, bfa[ks], acc0, 0, 0, 0);
      acc1 = __builtin_amdgcn_mfma_f32_16x16x32_bf16(af1, bfa[ks], acc1, 0, 0, 0);
    }
    const int col = nt * 16 + lr;
    const float bias = (col < 400) ? bq[col] : (col < 800) ? bk[col - 400] : bv[col - 800];
    #pragma unroll
    for (int i = 0; i < 4; ++i) {
      uB.qkv[(kg * 4 + i) * QKV_STR + col] = f2bf(acc0[i] + bias);     // rows 0..15
      const int r2 = 16 + kg * 4 + i;
      if (r2 < L_) uB.qkv[r2 * QKV_STR + col] = f2bf(acc1[i] + bias);  // rows 16..29
    }
  }
  __syncthreads();   // QKV ready; uA.x dead -> uA.p live

  // ---- attention: 40 (head, m-half) units over 16 waves ----
  ushort_t* pw = &uA.p[wave * (16 * P_STR)];
  for (int u = wave; u < 2 * H_; u += 16) {
    const int h = u >> 1, mt = u & 1;
    const int hq = h * AD_, hk = 400 + h * AD_, hv = 800 + h * AD_;

    // A (Q rows of this m-half) and B (both K halves), K=20 zero-masked
    bf16x8_t aq, bkf[2];
    {
      FragU fq;
      fq.u[0]=fq.u[1]=fq.u[2]=fq.u[3]=0;
      const bool okrow = (mt == 0) || (lr < 14);
      if (okrow && kg < 3) {
        const ushort_t* pq = &uB.qkv[(mt * 16 + lr) * QKV_STR + hq + kg * 8];
        fq.u[0] = *(const unsigned*)(pq);     fq.u[1] = *(const unsigned*)(pq + 2);
        if (kg < 2) { fq.u[2] = *(const unsigned*)(pq + 4); fq.u[3] = *(const unsigned*)(pq + 6); }
      }
      aq = fq.h;
    }
    #pragma unroll
    for (int t = 0; t < 2; ++t) {
      FragU fk;
      fk.u[0]=fk.u[1]=fk.u[2]=fk.u[3]=0;
      const bool okrow = (t == 0) || (lr < 14);
      if (okrow && kg < 3) {
        const ushort_t* pk = &uB.qkv[(t * 16 + lr) * QKV_STR + hk + kg * 8];
        fk.u[0] = *(const unsigned*)(pk);     fk.u[1] = *(const unsigned*)(pk + 2);
        if (kg < 2) { fk.u[2] = *(const unsigned*)(pk + 4); fk.u[3] = *(const unsigned*)(pk + 6); }
      }
      bkf[t] = fk.h;
    }
    f32x4_t c0 = {0,0,0,0}, c1 = {0,0,0,0};
    c0 = __builtin_amdgcn_mfma_f32_16x16x32_bf16(aq, bkf[0], c0, 0, 0, 0);
    c1 = __builtin_amdgcn_mfma_f32_16x16x32_bf16(aq, bkf[1], c1, 0, 0, 0);

    // in-register softmax over m; P (16 local rows) to per-wave LDS tile
    const float SCALE = 0.2236067977499790f;
    #pragma unroll
    for (int i = 0; i < 4; ++i) {
      const float v0 = c0[i] * SCALE;
      const float v1 = (lr < 14) ? c1[i] * SCALE : -1e30f;
      float mx = fmaxf(v0, v1);
      mx = fmaxf(mx, __shfl_xor(mx, 1));
      mx = fmaxf(mx, __shfl_xor(mx, 2));
      mx = fmaxf(mx, __shfl_xor(mx, 4));
      mx = fmaxf(mx, __shfl_xor(mx, 8));
      const float e0 = __expf(v0 - mx);
      const float e1 = (lr < 14) ? __expf(v1 - mx) : 0.f;
      float s = e0 + e1;
      s += __shfl_xor(s, 1);
      s += __shfl_xor(s, 2);
      s += __shfl_xor(s, 4);
      s += __shfl_xor(s, 8);
      const float inv = 1.f / s;
      const int row = kg * 4 + i;                 // local row 0..15
      pw[row * P_STR + lr]      = f2bf(e0 * inv);
      pw[row * P_STR + 16 + lr] = f2bf(e1 * inv);
    }
    __asm__ volatile("s_waitcnt lgkmcnt(0)" ::: "memory");

    // PV: A = P (16 rows, K=32 m; cols 30/31 zero), B = V columns
    bf16x8_t ap = *reinterpret_cast<const bf16x8_t*>(&pw[lr * P_STR + kg * 8]);
    bf16x8_t bvf[2];
    #pragma unroll
    for (int nt = 0; nt < 2; ++nt) {
      FragU f;
      const int d = nt * 16 + lr;
      if (d < AD_) {
        #pragma unroll
        for (int j = 0; j < 8; ++j) {
          const int rm = kg * 8 + j;
          f.s[j] = (rm < L_) ? (short)uB.qkv[rm * QKV_STR + hv + d] : (short)0;
        }
      } else {
        f.u[0]=f.u[1]=f.u[2]=f.u[3]=0;
      }
      bvf[nt] = f.h;
    }
    f32x4_t o0 = {0,0,0,0}, o1 = {0,0,0,0};
    o0 = __builtin_amdgcn_mfma_f32_16x16x32_bf16(ap, bvf[0], o0, 0, 0, 0);
    o1 = __builtin_amdgcn_mfma_f32_16x16x32_bf16(ap, bvf[1], o1, 0, 0, 0);

    #pragma unroll
    for (int nt = 0; nt < 2; ++nt) {
      const f32x4_t o = nt ? o1 : o0;
      const int d = nt * 16 + lr;
      if (d < AD_) {
        #pragma unroll
        for (int i = 0; i < 4; ++i) {
          const int r = mt * 16 + kg * 4 + i;
          if (r < L_) sOut[r * SOUT_STR + h * AD_ + d] = o[i];
        }
      }
    }
  }
  __syncthreads();

  // ---- LayerNorm rows ----
  for (int r = wave; r < L_; r += 16) {
    float s = 0.f, s2 = 0.f;
    for (int d = lane; d < MD_; d += 64) { const float v = sOut[r * SOUT_STR + d]; s += v; s2 += v * v; }
    s  = wave_reduce_sum(s);
    s2 = wave_reduce_sum(s2);
    const float mu  = s * (1.f / MD_);
    const float var = s2 * (1.f / MD_) - mu * mu;
    const float inv = rsqrtf(var + 1e-5f);
    for (int d = lane; d < MD_; d += 64)
      sOut[r * SOUT_STR + d] = (sOut[r * SOUT_STR + d] - mu) * inv * ln_g[d] + ln_b[d];
  }
  __syncthreads();

  // ---- bf16 copy of LN output (uB.qkv dead -> uB.o; rows 30/31 zero) ----
  {
    const int r = tid >> 5;          // 0..31
    const int c0 = tid & 31;
    #pragma unroll
    for (int k = 0; k < 13; ++k) {
      const int c = c0 + k * 32;
      if (c < 416) {
        const float v = (r < L_ && c < MD_) ? sOut[r * SOUT_STR + c] : 0.f;
        uB.o[r * OUTB_STR + c] = f2bf(v);
      }
    }
  }
  __syncthreads();

  // ---- additive attention scores via MFMA: [32,416] @ [416,208] ----
  for (int t = wave; t < 26; t += 16) {
    const int mt = t & 1, nt = t >> 1;
    f32x4_t acc = {0,0,0,0};
    const ushort_t* wbase = &Wat[(nt * 16 + lr) * WAT_K + kg * 8];
    bf16x8_t wfa[13];
    #pragma unroll
    for (int ks = 0; ks < 13; ++ks)
      wfa[ks] = *reinterpret_cast<const bf16x8_t*>(wbase + ks * 32);
    #pragma unroll
    for (int ks = 0; ks < 13; ++ks) {
      const int kb = ks * 32 + kg * 8;
      bf16x8_t af = *reinterpret_cast<const bf16x8_t*>(&uB.o[(mt * 16 + lr) * OUTB_STR + kb]);
      acc = __builtin_amdgcn_mfma_f32_16x16x32_bf16(af, wfa[ks], acc, 0, 0, 0);
    }
    const int q = nt * 16 + lr;
    if (q < QD_) {
      const float bb = wa_b[q], qq = wa_q[q];
      #pragma unroll
      for (int i = 0; i < 4; ++i) {
        const int row = mt * 16 + kg * 4 + i;
        if (row < L_) atomicAdd(&sSc[row], tanhf(acc[i] + bb) * qq);
      }
    }
  }
  __syncthreads();

  // ---- softmax over 30 positions (wave 0) ----
  if (wave == 0) {
    const float v = (lane < L_) ? sSc[lane] : -1e30f;
    float mx = v;
    #pragma unroll
    for (int off = 32; off > 0; off >>= 1) mx = fmaxf(mx, __shfl_xor(mx, off));
    const float e = (lane < L_) ? __expf(v - mx) : 0.f;
    float s = e;
    #pragma unroll
    for (int off = 32; off > 0; off >>= 1) s += __shfl_xor(s, off);
    if (lane < L_) sAlpha[lane] = e / s;
  }
  __syncthreads();

  if (tid < MD_) {
    const int d = tid;
    float acc = 0.f;
    #pragma unroll 6
    for (int l = 0; l < L_; ++l) acc += sAlpha[l] * sOut[l * SOUT_STR + d];
    word_rep[(size_t)b * MD_ + d] = tanhf(acc);
  }
}

// ---------------------------------------------------------------------------
// Entity branch (round-5 proven config): hi/lo 3-term MFMA on fc3, gcn, AND
// additive attention; g = A@e scalar f32. 512 thr, ~74.5 KB -> 2 blocks/CU.
// ---------------------------------------------------------------------------
__global__ __launch_bounds__(512, 4) void entity_branch_kernel(
    const float* __restrict__ Ein,
    const ushort_t* __restrict__ fc3TH, const ushort_t* __restrict__ fc3TL,
    const float* __restrict__ fc3_b,
    const float* __restrict__ gcn_A,
    const ushort_t* __restrict__ gcnTH, const ushort_t* __restrict__ gcnTL,
    const float* __restrict__ gcn_b,
    const float* __restrict__ ln_g, const float* __restrict__ ln_b,
    const ushort_t* __restrict__ eaTH, const ushort_t* __restrict__ eaTL,
    const float* __restrict__ ea_b, const float* __restrict__ ea_q,
    float* __restrict__ ent_rep)
{
  __shared__ __align__(16) ushort_t sEh[16 * 136], sEl[16 * 136];
  __shared__ __align__(16) float    eF[E_ * 104];          // e f32 [f][d]
  __shared__ __align__(16) ushort_t gH[16 * 136], gL[16 * 136];
  __shared__ __align__(16) float    sR[16 * SOUT_STR];
  __shared__ __align__(16) ushort_t oH[16 * OUTB_STR], oL[16 * OUTB_STR];
  __shared__ float sSc[16];
  __shared__ float sAlpha[16];

  const int b    = blockIdx.x;
  const int tid  = threadIdx.x;
  const int wave = tid >> 6;     // 0..7
  const int lane = tid & 63;
  const int lr   = lane & 15;
  const int kg   = lane >> 4;

  // stage E hi/lo -> [16][128] (pads zero); zero-init g tiles
  for (int id = tid; id < 16 * 128; id += 512) {
    const int r = id >> 7, c = id & 127;
    const float v = (r < E_ && c < ED_) ? Ein[(size_t)b * (E_ * ED_) + r * ED_ + c] : 0.f;
    const ushort_t hh = f2bf(v);
    sEh[r * 136 + c] = hh;
    sEl[r * 136 + c] = f2bf(v - bf2f(hh));
  }
  for (int id = tid; id < 16 * 136; id += 512) { gH[id] = 0; gL[id] = 0; }
  if (tid < 16) sSc[tid] = 0.f;
  __syncthreads();

  // fc3 (3-term): e = tanh(E @ fc3_w + b) -> eF f32 [f][d]
  for (int nt = wave; nt < 7; nt += 8) {
    f32x4_t acc = {0,0,0,0};
    #pragma unroll
    for (int ks = 0; ks < 4; ++ks) {
      const int kb = ks * 32 + kg * 8;
      bf16x8_t ah = *reinterpret_cast<const bf16x8_t*>(&sEh[lr * 136 + kb]);
      bf16x8_t al = *reinterpret_cast<const bf16x8_t*>(&sEl[lr * 136 + kb]);
      bf16x8_t wh = *reinterpret_cast<const bf16x8_t*>(&fc3TH[(nt * 16 + lr) * 128 + kb]);
      bf16x8_t wl = *reinterpret_cast<const bf16x8_t*>(&fc3TL[(nt * 16 + lr) * 128 + kb]);
      acc = __builtin_amdgcn_mfma_f32_16x16x32_bf16(ah, wh, acc, 0, 0, 0);
      acc = __builtin_amdgcn_mfma_f32_16x16x32_bf16(al, wh, acc, 0, 0, 0);
      acc = __builtin_amdgcn_mfma_f32_16x16x32_bf16(ah, wl, acc, 0, 0, 0);
    }
    const int d = nt * 16 + lr;
    if (d < ED_) {
      const float bias = fc3_b[d];
      #pragma unroll
      for (int i = 0; i < 4; ++i) {
        const int r = kg * 4 + i;
        if (r < E_) eF[r * 104 + d] = tanhf(acc[i] + bias);
      }
    }
  }
  __syncthreads();

  // g = A @ e, scalar f32 (1000 MACs) -> hi/lo bf16 tiles
  for (int id = tid; id < E_ * ED_; id += 512) {
    const int i = id / ED_, d = id - (id / ED_) * ED_;
    float acc = 0.f;
    #pragma unroll
    for (int f = 0; f < E_; ++f) acc += gcn_A[i * E_ + f] * eF[f * 104 + d];
    const ushort_t hh = f2bf(acc);
    gH[i * 136 + d] = hh;
    gL[i * 136 + d] = f2bf(acc - bf2f(hh));
  }
  __syncthreads();

  // r = relu(g @ gcn_w + b) (3-term) -> sR f32
  for (int nt = wave; nt < 25; nt += 8) {
    f32x4_t acc = {0,0,0,0};
    #pragma unroll
    for (int ks = 0; ks < 4; ++ks) {
      const int kb = ks * 32 + kg * 8;
      bf16x8_t ah = *reinterpret_cast<const bf16x8_t*>(&gH[lr * 136 + kb]);
      bf16x8_t al = *reinterpret_cast<const bf16x8_t*>(&gL[lr * 136 + kb]);
      bf16x8_t wh = *reinterpret_cast<const bf16x8_t*>(&gcnTH[(nt * 16 + lr) * 128 + kb]);
      bf16x8_t wl = *reinterpret_cast<const bf16x8_t*>(&gcnTL[(nt * 16 + lr) * 128 + kb]);
      acc = __builtin_amdgcn_mfma_f32_16x16x32_bf16(ah, wh, acc, 0, 0, 0);
      acc = __builtin_amdgcn_mfma_f32_16x16x32_bf16(al, wh, acc, 0, 0, 0);
      acc = __builtin_amdgcn_mfma_f32_16x16x32_bf16(ah, wl, acc, 0, 0, 0);
    }
    const int d = nt * 16 + lr;
    const float bias = gcn_b[d];
    #pragma unroll
    for (int i = 0; i < 4; ++i) {
      const int r = kg * 4 + i;
      if (r < E_) sR[r * SOUT_STR + d] = fmaxf(acc[i] + bias, 0.f);
    }
  }
  __syncthreads();

  // LayerNorm rows
  for (int r = wave; r < E_; r += 8) {
    float s = 0.f, s2 = 0.f;
    for (int d = lane; d < MD_; d += 64) { const float v = sR[r * SOUT_STR + d]; s += v; s2 += v * v; }
    s  = wave_reduce_sum(s);
    s2 = wave_reduce_sum(s2);
    const float mu  = s * (1.f / MD_);
    const float var = s2 * (1.f / MD_) - mu * mu;
    const float inv = rsqrtf(var + 1e-5f);
    for (int d = lane; d < MD_; d += 64)
      sR[r * SOUT_STR + d] = (sR[r * SOUT_STR + d] - mu) * inv * ln_g[d] + ln_b[d];
  }
  __syncthreads();

  // hi/lo bf16 copy for additive MFMA
  {
    const int r = tid >> 5;          // 0..15
    const int c0 = tid & 31;
    #pragma unroll
    for (int k = 0; k < 13; ++k) {
      const int c = c0 + k * 32;
      const float v = (r < E_ && c < MD_) ? sR[r * SOUT_STR + c] : 0.f;
      const ushort_t hh = f2bf(v);
      oH[r * OUTB_STR + c] = hh;
      oL[r * OUTB_STR + c] = f2bf(v - bf2f(hh));
    }
  }
  __syncthreads();

  // additive attention scores (3-term): [16,416] @ [416,208]
  for (int nt = wave; nt < 13; nt += 8) {
    f32x4_t acc = {0,0,0,0};
    for (int ks = 0; ks < 13; ++ks) {
      const int kb = ks * 32 + kg * 8;
      bf16x8_t ah = *reinterpret_cast<const bf16x8_t*>(&oH[lr * OUTB_STR + kb]);
      bf16x8_t al = *reinterpret_cast<const bf16x8_t*>(&oL[lr * OUTB_STR + kb]);
      bf16x8_t wh = *reinterpret_cast<const bf16x8_t*>(&eaTH[(nt * 16 + lr) * WAT_K + kb]);
      bf16x8_t wl = *reinterpret_cast<const bf16x8_t*>(&eaTL[(nt * 16 + lr) * WAT_K + kb]);
      acc = __builtin_amdgcn_mfma_f32_16x16x32_bf16(ah, wh, acc, 0, 0, 0);
      acc = __builtin_amdgcn_mfma_f32_16x16x32_bf16(al, wh, acc, 0, 0, 0);
      acc = __builtin_amdgcn_mfma_f32_16x16x32_bf16(ah, wl, acc, 0, 0, 0);
    }
    const int q = nt * 16 + lr;
    if (q < QD_) {
      const float bb = ea_b[q], qq = ea_q[q];
      #pragma unroll
      for (int i = 0; i < 4; ++i) {
        const int r = kg * 4 + i;
        if (r < E_) atomicAdd(&sSc[r], tanhf(acc[i] + bb) * qq);
      }
    }
  }
  __syncthreads();

  if (wave == 0) {
    const float v = (lane < E_) ? sSc[lane] : -1e30f;
    float mx = v;
    #pragma unroll
    for (int off = 32; off > 0; off >>= 1) mx = fmaxf(mx, __shfl_xor(mx, off));
    const float e = (lane < E_) ? __expf(v - mx) : 0.f;
    float s = e;
    #pragma unroll
    for (int off = 32; off > 0; off >>= 1) s += __shfl_xor(s, off);
    if (lane < E_) sAlpha[lane] = e / s;
  }
  __syncthreads();

  if (tid < MD_) {
    const int d = tid;
    float acc = 0.f;
    #pragma unroll
    for (int i = 0; i < E_; ++i) acc += sAlpha[i] * sR[i * SOUT_STR + d];
    ent_rep[(size_t)b * MD_ + d] = tanhf(acc);
  }
}

// ---------------------------------------------------------------------------
__global__ __launch_bounds__(256) void catsub_kernel(
    const int* __restrict__ cat_idx, const int* __restrict__ sub_idx,
    const float* __restrict__ emb_cat, const float* __restrict__ fc1_w, const float* __restrict__ fc1_b,
    const float* __restrict__ emb_sub, const float* __restrict__ fc2_w, const float* __restrict__ fc2_b,
    float* __restrict__ cat_rep, float* __restrict__ sub_rep)
{
  int idx = blockIdx.x * 256 + threadIdx.x;
  const int total = B_ * MD_;
  if (idx < total) {
    const int b = idx / MD_, d = idx - (idx / MD_) * MD_;
    const float* row = emb_cat + (size_t)cat_idx[b] * CD_;
    float acc = fc1_b[d];
    #pragma unroll
    for (int k = 0; k < CD_; ++k) acc += row[k] * fc1_w[k * MD_ + d];
    cat_rep[idx] = tanhf(acc);
  } else {
    idx -= total;
    if (idx < total) {
      const int b = idx / MD_, d = idx - (idx / MD_) * MD_;
      const float* row = emb_sub + (size_t)sub_idx[b] * SD_;
      float acc = fc2_b[d];
      #pragma unroll
      for (int k = 0; k < SD_; ++k) acc += row[k] * fc2_w[k * MD_ + d];
      sub_rep[idx] = tanhf(acc);
    }
  }
}

// ---------------------------------------------------------------------------
__global__ __launch_bounds__(256) void fuse_kernel(
    const float* __restrict__ word_rep, const float* __restrict__ ent_rep,
    const float* __restrict__ cat_rep, const float* __restrict__ sub_rep,
    const float* __restrict__ na_w, const float* __restrict__ na_b, const float* __restrict__ na_q,
    float* __restrict__ out)
{
  __shared__ float sViews[4][MD_];
  __shared__ float sSc[4];
  __shared__ float sAlpha[4];
  const int b = blockIdx.x, tid = threadIdx.x;
  for (int d = tid; d < MD_; d += 256) {
    sViews[0][d] = word_rep[(size_t)b * MD_ + d];
    sViews[1][d] = ent_rep[(size_t)b * MD_ + d];
    sViews[2][d] = cat_rep[(size_t)b * MD_ + d];
    sViews[3][d] = sub_rep[(size_t)b * MD_ + d];
  }
  if (tid < 4) sSc[tid] = 0.f;
  __syncthreads();
  for (int id = tid; id < 4 * QD_; id += 256) {
    const int v = id / QD_, q = id - (id / QD_) * QD_;
    float acc = na_b[q];
    #pragma unroll 4
    for (int d = 0; d < MD_; ++d) acc += sViews[v][d] * na_w[d * QD_ + q];
    atomicAdd(&sSc[v], tanhf(acc) * na_q[q]);
  }
  __syncthreads();
  if (tid == 0) {
    float mx = -1e30f;
    for (int v = 0; v < 4; ++v) mx = fmaxf(mx, sSc[v]);
    float sum = 0.f;
    for (int v = 0; v < 4; ++v) { const float e = __expf(sSc[v] - mx); sAlpha[v] = e; sum += e; }
    const float inv = 1.f / sum;
    for (int v = 0; v < 4; ++v) sAlpha[v] *= inv;
  }
  __syncthreads();
  for (int d = tid; d < MD_; d += 256) {
    const float acc = sAlpha[0] * sViews[0][d] + sAlpha[1] * sViews[1][d] +
                      sAlpha[2] * sViews[2][d] + sAlpha[3] * sViews[3][d];
    out[(size_t)b * MD_ + d] = tanhf(acc);
  }
}

// ---------------------------------------------------------------------------
extern "C" void kernel_launch(void* const* d_in, const int* in_sizes, int n_in,
                              void* d_out, int out_size, void* d_ws, size_t ws_size,
                              hipStream_t stream) {
  const float* X        = (const float*)d_in[0];
  const float* Ein      = (const float*)d_in[1];
  const int*   cat_idx  = (const int*)d_in[2];
  const int*   sub_idx  = (const int*)d_in[3];
  const float* emb_cat  = (const float*)d_in[4];
  const float* fc1_w    = (const float*)d_in[5];
  const float* fc1_b    = (const float*)d_in[6];
  const float* emb_sub  = (const float*)d_in[7];
  const float* fc2_w    = (const float*)d_in[8];
  const float* fc2_b    = (const float*)d_in[9];
  const float* wq       = (const float*)d_in[10];
  const float* bq       = (const float*)d_in[11];
  const float* wk       = (const float*)d_in[12];
  const float* bk       = (const float*)d_in[13];
  const float* wv       = (const float*)d_in[14];
  const float* bv       = (const float*)d_in[15];
  const float* ln_g     = (const float*)d_in[16];
  const float* ln_b     = (const float*)d_in[17];
  const float* wa_w     = (const float*)d_in[18];
  const float* wa_b     = (const float*)d_in[19];
  const float* wa_q     = (const float*)d_in[20];
  const float* fc3_w    = (const float*)d_in[21];
  const float* fc3_b    = (const float*)d_in[22];
  const float* gcn_A    = (const float*)d_in[23];
  const float* gcn_w    = (const float*)d_in[24];
  const float* gcn_b    = (const float*)d_in[25];
  const float* ea_w     = (const float*)d_in[26];
  const float* ea_b     = (const float*)d_in[27];
  const float* ea_q     = (const float*)d_in[28];
  const float* na_w     = (const float*)d_in[29];
  const float* na_b     = (const float*)d_in[30];
  const float* na_q     = (const float*)d_in[31];

  float* out = (float*)d_out;
  const size_t BM = (size_t)B_ * MD_;
  float* word_rep = (float*)d_ws;
  float* ent_rep  = word_rep + BM;
  float* cat_rep  = ent_rep + BM;
  float* sub_rep  = cat_rep + BM;
  ushort_t* Wt    = (ushort_t*)(sub_rep + BM);
  ushort_t* Wat   = Wt + N_WT;
  ushort_t* fc3TH = Wat + N_WAT;
  ushort_t* fc3TL = fc3TH + N_FC3T;
  ushort_t* gcnTH = fc3TL + N_FC3T;
  ushort_t* gcnTL = gcnTH + N_GCNT;
  ushort_t* eaTH  = gcnTL + N_GCNT;
  ushort_t* eaTL  = eaTH + N_EAT;

  {
    const int total = N_WT + N_WAT + N_FC3T + N_GCNT + N_EAT;
    prep_weights<<<(total + 255) / 256, 256, 0, stream>>>(
        wq, wk, wv, wa_w, fc3_w, gcn_w, ea_w,
        Wt, Wat, fc3TH, fc3TL, gcnTH, gcnTL, eaTH, eaTL);
  }
  word_branch_kernel<<<B_, 1024, 0, stream>>>(X, Wt, Wat, bq, bk, bv,
                                              ln_g, ln_b, wa_b, wa_q, word_rep);
  entity_branch_kernel<<<B_, 512, 0, stream>>>(Ein, fc3TH, fc3TL, fc3_b, gcn_A,
                                               gcnTH, gcnTL, gcn_b,
                                               ln_g, ln_b, eaTH, eaTL, ea_b, ea_q, ent_rep);
  catsub_kernel<<<(2 * B_ * MD_) / 256, 256, 0, stream>>>(cat_idx, sub_idx,
                                                          emb_cat, fc1_w, fc1_b,
                                                          emb_sub, fc2_w, fc2_b,
                                                          cat_rep, sub_rep);
  fuse_kernel<<<B_, 256, 0, stream>>>(word_rep, ent_rep, cat_rep, sub_rep,
                                      na_w, na_b, na_q, out);
}

// Round 8
// 1311.006 us; speedup vs baseline: 16.2407x; 1.0092x over previous
//
#include <hip/hip_runtime.h>
#include <hip/hip_bf16.h>
#include <math.h>

#define B_  4096
#define L_  30
#define WD_ 300
#define H_  20
#define AD_ 20
#define MD_ 400
#define E_  10
#define ED_ 100
#define QD_ 200
#define CD_ 50
#define SD_ 50

typedef unsigned short ushort_t;
typedef __attribute__((ext_vector_type(8))) short bf16x8_t;
typedef __attribute__((ext_vector_type(4))) float f32x4_t;

// strides (elements)
#define SX_STR   328      // staged X row stride (320 + 8)
#define QKV_STR  1218     // QKV row stride (30 rows only)
#define OUTB_STR 424      // LN-out bf16 row stride (32 rows, 30/31 zeroed)
#define SOUT_STR 401      // f32 MHA-out row stride (odd -> bank spread)
#define P_STR    40       // bf16 P row stride (per-wave tile 16 x 40)
#define WT_K     320      // Wqkv K-extent (300 pad 320)
#define WAT_K    416      // Wa/Ea K-extent (400 pad 416)

// prep array sizes (elements per array)
#define N_WT    (1200 * WT_K)
#define N_WAT   (208 * WAT_K)
#define N_FC3T  (112 * 128)
#define N_GCNT  (400 * 128)
#define N_EAT   (208 * WAT_K)

union FragU {
  unsigned  u[4];
  short     s[8];
  bf16x8_t  h;
};

__device__ __forceinline__ ushort_t f2bf(float f) {
  unsigned u = __builtin_bit_cast(unsigned, f);
  unsigned r = (u + 0x7fffu + ((u >> 16) & 1u)) >> 16;
  return (ushort_t)r;
}
__device__ __forceinline__ float bf2f(ushort_t h) {
  return __builtin_bit_cast(float, ((unsigned)h) << 16);
}
__device__ __forceinline__ float wave_reduce_sum(float v) {
  #pragma unroll
  for (int off = 32; off > 0; off >>= 1) v += __shfl_xor(v, off);
  return v;
}
__device__ __forceinline__ void split2(float v, ushort_t* __restrict__ H,
                                       ushort_t* __restrict__ Lo, int idx) {
  const ushort_t h = f2bf(v);
  H[idx] = h;
  Lo[idx] = f2bf(v - bf2f(h));
}

// ---------------------------------------------------------------------------
// Weight prep: Wt, Wat single-bf16; fc3/gcn/ea hi/lo pairs (entity branch
// REQUIRES 3-term everywhere incl. additive — single-term ea failed r6 at
// absmax 5e-2; the E=10 sharp softmax amplifies bf16 score noise).
// ---------------------------------------------------------------------------
__global__ __launch_bounds__(256) void prep_weights(
    const float* __restrict__ wq, const float* __restrict__ wk, const float* __restrict__ wv,
    const float* __restrict__ wa_w, const float* __restrict__ fc3_w,
    const float* __restrict__ gcn_w, const float* __restrict__ ea_w,
    ushort_t* __restrict__ Wt, ushort_t* __restrict__ Wat,
    ushort_t* __restrict__ fc3TH, ushort_t* __restrict__ fc3TL,
    ushort_t* __restrict__ gcnTH, ushort_t* __restrict__ gcnTL,
    ushort_t* __restrict__ eaTH, ushort_t* __restrict__ eaTL)
{
  int idx = blockIdx.x * 256 + threadIdx.x;
  if (idx < N_WT) {
    const int n = idx / WT_K, k = idx - n * WT_K;
    float v = 0.f;
    if (k < WD_) {
      const float* w = (n < 400) ? wq : (n < 800) ? wk : wv;
      const int c = (n < 400) ? n : (n < 800) ? n - 400 : n - 800;
      v = w[k * MD_ + c];
    }
    Wt[idx] = f2bf(v);
    return;
  }
  idx -= N_WT;
  if (idx < N_WAT) {
    const int q = idx / WAT_K, d = idx - q * WAT_K;
    Wat[idx] = (q < QD_ && d < MD_) ? f2bf(wa_w[d * QD_ + q]) : (ushort_t)0;
    return;
  }
  idx -= N_WAT;
  if (idx < N_FC3T) {
    const int n = idx / 128, k = idx - n * 128;
    const float v = (n < ED_ && k < ED_) ? fc3_w[k * ED_ + n] : 0.f;
    split2(v, fc3TH, fc3TL, idx);
    return;
  }
  idx -= N_FC3T;
  if (idx < N_GCNT) {
    const int n = idx / 128, k = idx - n * 128;
    const float v = (k < ED_) ? gcn_w[k * MD_ + n] : 0.f;
    split2(v, gcnTH, gcnTL, idx);
    return;
  }
  idx -= N_GCNT;
  if (idx < N_EAT) {
    const int q = idx / WAT_K, d = idx - q * WAT_K;
    const float v = (q < QD_ && d < MD_) ? ea_w[d * QD_ + q] : 0.f;
    split2(v, eaTH, eaTL, idx);
  }
}

// ---------------------------------------------------------------------------
// Word branch. 1024 thr (16 waves, 4/SIMD). LDS ~142 KB.
// QKV: A-fragments hoisted to registers (80 VGPR), B streamed from L2.
// ---------------------------------------------------------------------------
__global__ __launch_bounds__(1024, 4) void word_branch_kernel(
    const float* __restrict__ X,
    const ushort_t* __restrict__ Wt, const ushort_t* __restrict__ Wat,
    const float* __restrict__ bq, const float* __restrict__ bk, const float* __restrict__ bv,
    const float* __restrict__ ln_g, const float* __restrict__ ln_b,
    const float* __restrict__ wa_b, const float* __restrict__ wa_q,
    float* __restrict__ word_rep)
{
  __shared__ __align__(16) union {
    ushort_t x[32 * SX_STR];               // 20,992 B staged X
    ushort_t p[16 * 16 * P_STR];           // 20,480 B per-wave bf16 P half-tiles
  } uA;
  __shared__ __align__(16) union {
    ushort_t qkv[30 * QKV_STR];            // 73,080 B (rows 0..29)
    ushort_t o[32 * OUTB_STR];             // 27,136 B LN-out bf16 (after attn)
  } uB;
  __shared__ __align__(16) float sOut[30 * SOUT_STR];  // 48,120 B
  __shared__ float sSc[32];
  __shared__ float sAlpha[32];

  const int b    = blockIdx.x;
  const int tid  = threadIdx.x;
  const int wave = tid >> 6;     // 0..15
  const int lane = tid & 63;
  const int lr   = lane & 15;
  const int kg   = lane >> 4;

  // ---- stage X -> bf16 [32][320] (zero pads) ----
  const float* xb = X + (size_t)b * (L_ * WD_);
  {
    const int r = tid >> 5;          // 0..31
    const int c0 = tid & 31;
    #pragma unroll
    for (int k = 0; k < 10; ++k) {
      const int c = c0 + k * 32;
      const float v = (r < L_ && c < WD_) ? xb[r * WD_ + c] : 0.f;
      uA.x[r * SX_STR + c] = f2bf(v);
    }
  }
  if (tid < 32) sSc[tid] = 0.f;
  __syncthreads();

  // ---- QKV GEMM: [32,320] @ [320,1200] ----
  // A-fragments loop-invariant across all 75 N-units -> hoist to registers.
  bf16x8_t axl[10], axh[10];
  #pragma unroll
  for (int ks = 0; ks < 10; ++ks) {
    axl[ks] = *reinterpret_cast<const bf16x8_t*>(&uA.x[lr * SX_STR + ks * 32 + kg * 8]);
    axh[ks] = *reinterpret_cast<const bf16x8_t*>(&uA.x[(16 + lr) * SX_STR + ks * 32 + kg * 8]);
  }
  for (int nt = wave; nt < 75; nt += 16) {
    const ushort_t* wbase = &Wt[(nt * 16 + lr) * WT_K + kg * 8];
    f32x4_t acc0 = {0,0,0,0}, acc1 = {0,0,0,0};
    #pragma unroll
    for (int ks = 0; ks < 10; ++ks) {
      bf16x8_t bf = *reinterpret_cast<const bf16x8_t*>(wbase + ks * 32);
      acc0 = __builtin_amdgcn_mfma_f32_16x16x32_bf16(axl[ks], bf, acc0, 0, 0, 0);
      acc1 = __builtin_amdgcn_mfma_f32_16x16x32_bf16(axh[ks], bf, acc1, 0, 0, 0);
    }
    const int col = nt * 16 + lr;
    const float bias = (col < 400) ? bq[col] : (col < 800) ? bk[col - 400] : bv[col - 800];
    #pragma unroll
    for (int i = 0; i < 4; ++i) {
      uB.qkv[(kg * 4 + i) * QKV_STR + col] = f2bf(acc0[i] + bias);     // rows 0..15
      const int r2 = 16 + kg * 4 + i;
      if (r2 < L_) uB.qkv[r2 * QKV_STR + col] = f2bf(acc1[i] + bias);  // rows 16..29
    }
  }
  __syncthreads();   // QKV ready; uA.x dead -> uA.p live

  // ---- attention: 40 (head, m-half) units over 16 waves ----
  ushort_t* pw = &uA.p[wave * (16 * P_STR)];
  for (int u = wave; u < 2 * H_; u += 16) {
    const int h = u >> 1, mt = u & 1;
    const int hq = h * AD_, hk = 400 + h * AD_, hv = 800 + h * AD_;

    // A (Q rows of this m-half) and B (both K halves), K=20 zero-masked
    bf16x8_t aq, bkf[2];
    {
      FragU fq;
      fq.u[0]=fq.u[1]=fq.u[2]=fq.u[3]=0;
      const bool okrow = (mt == 0) || (lr < 14);
      if (okrow && kg < 3) {
        const ushort_t* pq = &uB.qkv[(mt * 16 + lr) * QKV_STR + hq + kg * 8];
        fq.u[0] = *(const unsigned*)(pq);     fq.u[1] = *(const unsigned*)(pq + 2);
        if (kg < 2) { fq.u[2] = *(const unsigned*)(pq + 4); fq.u[3] = *(const unsigned*)(pq + 6); }
      }
      aq = fq.h;
    }
    #pragma unroll
    for (int t = 0; t < 2; ++t) {
      FragU fk;
      fk.u[0]=fk.u[1]=fk.u[2]=fk.u[3]=0;
      const bool okrow = (t == 0) || (lr < 14);
      if (okrow && kg < 3) {
        const ushort_t* pk = &uB.qkv[(t * 16 + lr) * QKV_STR + hk + kg * 8];
        fk.u[0] = *(const unsigned*)(pk);     fk.u[1] = *(const unsigned*)(pk + 2);
        if (kg < 2) { fk.u[2] = *(const unsigned*)(pk + 4); fk.u[3] = *(const unsigned*)(pk + 6); }
      }
      bkf[t] = fk.h;
    }
    f32x4_t c0 = {0,0,0,0}, c1 = {0,0,0,0};
    c0 = __builtin_amdgcn_mfma_f32_16x16x32_bf16(aq, bkf[0], c0, 0, 0, 0);
    c1 = __builtin_amdgcn_mfma_f32_16x16x32_bf16(aq, bkf[1], c1, 0, 0, 0);

    // in-register softmax over m; P (16 local rows) to per-wave LDS tile
    const float SCALE = 0.2236067977499790f;
    #pragma unroll
    for (int i = 0; i < 4; ++i) {
      const float v0 = c0[i] * SCALE;
      const float v1 = (lr < 14) ? c1[i] * SCALE : -1e30f;
      float mx = fmaxf(v0, v1);
      mx = fmaxf(mx, __shfl_xor(mx, 1));
      mx = fmaxf(mx, __shfl_xor(mx, 2));
      mx = fmaxf(mx, __shfl_xor(mx, 4));
      mx = fmaxf(mx, __shfl_xor(mx, 8));
      const float e0 = __expf(v0 - mx);
      const float e1 = (lr < 14) ? __expf(v1 - mx) : 0.f;
      float s = e0 + e1;
      s += __shfl_xor(s, 1);
      s += __shfl_xor(s, 2);
      s += __shfl_xor(s, 4);
      s += __shfl_xor(s, 8);
      const float inv = 1.f / s;
      const int row = kg * 4 + i;                 // local row 0..15
      pw[row * P_STR + lr]      = f2bf(e0 * inv);
      pw[row * P_STR + 16 + lr] = f2bf(e1 * inv);
    }
    __asm__ volatile("s_waitcnt lgkmcnt(0)" ::: "memory");

    // PV: A = P (16 rows, K=32 m; cols 30/31 zero), B = V columns
    bf16x8_t ap = *reinterpret_cast<const bf16x8_t*>(&pw[lr * P_STR + kg * 8]);
    bf16x8_t bvf[2];
    #pragma unroll
    for (int nt = 0; nt < 2; ++nt) {
      FragU f;
      const int d = nt * 16 + lr;
      if (d < AD_) {
        #pragma unroll
        for (int j = 0; j < 8; ++j) {
          const int rm = kg * 8 + j;
          f.s[j] = (rm < L_) ? (short)uB.qkv[rm * QKV_STR + hv + d] : (short)0;
        }
      } else {
        f.u[0]=f.u[1]=f.u[2]=f.u[3]=0;
      }
      bvf[nt] = f.h;
    }
    f32x4_t o0 = {0,0,0,0}, o1 = {0,0,0,0};
    o0 = __builtin_amdgcn_mfma_f32_16x16x32_bf16(ap, bvf[0], o0, 0, 0, 0);
    o1 = __builtin_amdgcn_mfma_f32_16x16x32_bf16(ap, bvf[1], o1, 0, 0, 0);

    #pragma unroll
    for (int nt = 0; nt < 2; ++nt) {
      const f32x4_t o = nt ? o1 : o0;
      const int d = nt * 16 + lr;
      if (d < AD_) {
        #pragma unroll
        for (int i = 0; i < 4; ++i) {
          const int r = mt * 16 + kg * 4 + i;
          if (r < L_) sOut[r * SOUT_STR + h * AD_ + d] = o[i];
        }
      }
    }
  }
  __syncthreads();   // attention done; uB.qkv dead -> uB.o live

  // ---- LayerNorm rows (writes f32 AND bf16 copy inline) + o-pad zeroing ----
  for (int r = wave; r < L_; r += 16) {
    float s = 0.f, s2 = 0.f;
    for (int d = lane; d < MD_; d += 64) { const float v = sOut[r * SOUT_STR + d]; s += v; s2 += v * v; }
    s  = wave_reduce_sum(s);
    s2 = wave_reduce_sum(s2);
    const float mu  = s * (1.f / MD_);
    const float var = s2 * (1.f / MD_) - mu * mu;
    const float inv = rsqrtf(var + 1e-5f);
    for (int d = lane; d < MD_; d += 64) {
      const float nv = (sOut[r * SOUT_STR + d] - mu) * inv * ln_g[d] + ln_b[d];
      sOut[r * SOUT_STR + d] = nv;
      uB.o[r * OUTB_STR + d] = f2bf(nv);
    }
  }
  // zero pad cells of uB.o: rows 30/31 (cols 0..415), cols 400..415 (rows 0..29)
  if (tid < 2 * 416) {
    const int r = 30 + (tid / 416), c = tid - (tid / 416) * 416;
    uB.o[r * OUTB_STR + c] = 0;
  }
  {
    const int id = tid;
    if (id < 30 * 16) {
      const int r = id >> 4, c = 400 + (id & 15);
      uB.o[r * OUTB_STR + c] = 0;
    }
  }
  __syncthreads();

  // ---- additive attention scores via MFMA: [32,416] @ [416,208] ----
  // A-frags prefetched to regs, weights streamed from L2.
  for (int t = wave; t < 26; t += 16) {
    const int mt = t & 1, nt = t >> 1;
    bf16x8_t afa[13];
    #pragma unroll
    for (int ks = 0; ks < 13; ++ks)
      afa[ks] = *reinterpret_cast<const bf16x8_t*>(&uB.o[(mt * 16 + lr) * OUTB_STR + ks * 32 + kg * 8]);
    const ushort_t* wbase = &Wat[(nt * 16 + lr) * WAT_K + kg * 8];
    f32x4_t acc = {0,0,0,0};
    #pragma unroll
    for (int ks = 0; ks < 13; ++ks) {
      bf16x8_t wf = *reinterpret_cast<const bf16x8_t*>(wbase + ks * 32);
      acc = __builtin_amdgcn_mfma_f32_16x16x32_bf16(afa[ks], wf, acc, 0, 0, 0);
    }
    const int q = nt * 16 + lr;
    if (q < QD_) {
      const float bb = wa_b[q], qq = wa_q[q];
      #pragma unroll
      for (int i = 0; i < 4; ++i) {
        const int row = mt * 16 + kg * 4 + i;
        if (row < L_) atomicAdd(&sSc[row], tanhf(acc[i] + bb) * qq);
      }
    }
  }
  __syncthreads();

  // ---- softmax over 30 positions (wave 0) ----
  if (wave == 0) {
    const float v = (lane < L_) ? sSc[lane] : -1e30f;
    float mx = v;
    #pragma unroll
    for (int off = 32; off > 0; off >>= 1) mx = fmaxf(mx, __shfl_xor(mx, off));
    const float e = (lane < L_) ? __expf(v - mx) : 0.f;
    float s = e;
    #pragma unroll
    for (int off = 32; off > 0; off >>= 1) s += __shfl_xor(s, off);
    if (lane < L_) sAlpha[lane] = e / s;
  }
  __syncthreads();

  if (tid < MD_) {
    const int d = tid;
    float acc = 0.f;
    #pragma unroll 6
    for (int l = 0; l < L_; ++l) acc += sAlpha[l] * sOut[l * SOUT_STR + d];
    word_rep[(size_t)b * MD_ + d] = tanhf(acc);
  }
}

// ---------------------------------------------------------------------------
// Entity branch (r5/r7 proven math): hi/lo 3-term MFMA on fc3, gcn, AND
// additive; g = A@e scalar f32. 512 thr, ~74.5 KB -> 2 blocks/CU.
// LN copy folded; oH/oL pads zeroed in staging.
// ---------------------------------------------------------------------------
__global__ __launch_bounds__(512, 4) void entity_branch_kernel(
    const float* __restrict__ Ein,
    const ushort_t* __restrict__ fc3TH, const ushort_t* __restrict__ fc3TL,
    const float* __restrict__ fc3_b,
    const float* __restrict__ gcn_A,
    const ushort_t* __restrict__ gcnTH, const ushort_t* __restrict__ gcnTL,
    const float* __restrict__ gcn_b,
    const float* __restrict__ ln_g, const float* __restrict__ ln_b,
    const ushort_t* __restrict__ eaTH, const ushort_t* __restrict__ eaTL,
    const float* __restrict__ ea_b, const float* __restrict__ ea_q,
    float* __restrict__ ent_rep)
{
  __shared__ __align__(16) ushort_t sEh[16 * 136], sEl[16 * 136];
  __shared__ __align__(16) float    eF[E_ * 104];          // e f32 [f][d]
  __shared__ __align__(16) ushort_t gH[16 * 136], gL[16 * 136];
  __shared__ __align__(16) float    sR[16 * SOUT_STR];
  __shared__ __align__(16) ushort_t oH[16 * OUTB_STR], oL[16 * OUTB_STR];
  __shared__ float sSc[16];
  __shared__ float sAlpha[16];

  const int b    = blockIdx.x;
  const int tid  = threadIdx.x;
  const int wave = tid >> 6;     // 0..7
  const int lane = tid & 63;
  const int lr   = lane & 15;
  const int kg   = lane >> 4;

  // stage E hi/lo -> [16][128] (pads zero); zero g tiles and ALL of oH/oL
  for (int id = tid; id < 16 * 128; id += 512) {
    const int r = id >> 7, c = id & 127;
    const float v = (r < E_ && c < ED_) ? Ein[(size_t)b * (E_ * ED_) + r * ED_ + c] : 0.f;
    const ushort_t hh = f2bf(v);
    sEh[r * 136 + c] = hh;
    sEl[r * 136 + c] = f2bf(v - bf2f(hh));
  }
  for (int id = tid; id < 16 * 136; id += 512) { gH[id] = 0; gL[id] = 0; }
  for (int id = tid; id < 16 * OUTB_STR; id += 512) { oH[id] = 0; oL[id] = 0; }
  if (tid < 16) sSc[tid] = 0.f;
  __syncthreads();

  // fc3 (3-term): e = tanh(E @ fc3_w + b) -> eF f32 [f][d]
  for (int nt = wave; nt < 7; nt += 8) {
    f32x4_t acc = {0,0,0,0};
    #pragma unroll
    for (int ks = 0; ks < 4; ++ks) {
      const int kb = ks * 32 + kg * 8;
      bf16x8_t ah = *reinterpret_cast<const bf16x8_t*>(&sEh[lr * 136 + kb]);
      bf16x8_t al = *reinterpret_cast<const bf16x8_t*>(&sEl[lr * 136 + kb]);
      bf16x8_t wh = *reinterpret_cast<const bf16x8_t*>(&fc3TH[(nt * 16 + lr) * 128 + kb]);
      bf16x8_t wl = *reinterpret_cast<const bf16x8_t*>(&fc3TL[(nt * 16 + lr) * 128 + kb]);
      acc = __builtin_amdgcn_mfma_f32_16x16x32_bf16(ah, wh, acc, 0, 0, 0);
      acc = __builtin_amdgcn_mfma_f32_16x16x32_bf16(al, wh, acc, 0, 0, 0);
      acc = __builtin_amdgcn_mfma_f32_16x16x32_bf16(ah, wl, acc, 0, 0, 0);
    }
    const int d = nt * 16 + lr;
    if (d < ED_) {
      const float bias = fc3_b[d];
      #pragma unroll
      for (int i = 0; i < 4; ++i) {
        const int r = kg * 4 + i;
        if (r < E_) eF[r * 104 + d] = tanhf(acc[i] + bias);
      }
    }
  }
  __syncthreads();

  // g = A @ e, scalar f32 (1000 MACs) -> hi/lo bf16 tiles
  for (int id = tid; id < E_ * ED_; id += 512) {
    const int i = id / ED_, d = id - (id / ED_) * ED_;
    float acc = 0.f;
    #pragma unroll
    for (int f = 0; f < E_; ++f) acc += gcn_A[i * E_ + f] * eF[f * 104 + d];
    const ushort_t hh = f2bf(acc);
    gH[i * 136 + d] = hh;
    gL[i * 136 + d] = f2bf(acc - bf2f(hh));
  }
  __syncthreads();

  // r = relu(g @ gcn_w + b) (3-term) -> sR f32
  for (int nt = wave; nt < 25; nt += 8) {
    f32x4_t acc = {0,0,0,0};
    #pragma unroll
    for (int ks = 0; ks < 4; ++ks) {
      const int kb = ks * 32 + kg * 8;
      bf16x8_t ah = *reinterpret_cast<const bf16x8_t*>(&gH[lr * 136 + kb]);
      bf16x8_t al = *reinterpret_cast<const bf16x8_t*>(&gL[lr * 136 + kb]);
      bf16x8_t wh = *reinterpret_cast<const bf16x8_t*>(&gcnTH[(nt * 16 + lr) * 128 + kb]);
      bf16x8_t wl = *reinterpret_cast<const bf16x8_t*>(&gcnTL[(nt * 16 + lr) * 128 + kb]);
      acc = __builtin_amdgcn_mfma_f32_16x16x32_bf16(ah, wh, acc, 0, 0, 0);
      acc = __builtin_amdgcn_mfma_f32_16x16x32_bf16(al, wh, acc, 0, 0, 0);
      acc = __builtin_amdgcn_mfma_f32_16x16x32_bf16(ah, wl, acc, 0, 0, 0);
    }
    const int d = nt * 16 + lr;
    const float bias = gcn_b[d];
    #pragma unroll
    for (int i = 0; i < 4; ++i) {
      const int r = kg * 4 + i;
      if (r < E_) sR[r * SOUT_STR + d] = fmaxf(acc[i] + bias, 0.f);
    }
  }
  __syncthreads();

  // LayerNorm rows (writes f32 AND hi/lo bf16 copies inline)
  for (int r = wave; r < E_; r += 8) {
    float s = 0.f, s2 = 0.f;
    for (int d = lane; d < MD_; d += 64) { const float v = sR[r * SOUT_STR + d]; s += v; s2 += v * v; }
    s  = wave_reduce_sum(s);
    s2 = wave_reduce_sum(s2);
    const float mu  = s * (1.f / MD_);
    const float var = s2 * (1.f / MD_) - mu * mu;
    const float inv = rsqrtf(var + 1e-5f);
    for (int d = lane; d < MD_; d += 64) {
      const float nv = (sR[r * SOUT_STR + d] - mu) * inv * ln_g[d] + ln_b[d];
      sR[r * SOUT_STR + d] = nv;
      const ushort_t hh = f2bf(nv);
      oH[r * OUTB_STR + d] = hh;
      oL[r * OUTB_STR + d] = f2bf(nv - bf2f(hh));
    }
  }
  __syncthreads();

  // additive attention scores (3-term): [16,416] @ [416,208]
  for (int nt = wave; nt < 13; nt += 8) {
    f32x4_t acc = {0,0,0,0};
    for (int ks = 0; ks < 13; ++ks) {
      const int kb = ks * 32 + kg * 8;
      bf16x8_t ah = *reinterpret_cast<const bf16x8_t*>(&oH[lr * OUTB_STR + kb]);
      bf16x8_t al = *reinterpret_cast<const bf16x8_t*>(&oL[lr * OUTB_STR + kb]);
      bf16x8_t wh = *reinterpret_cast<const bf16x8_t*>(&eaTH[(nt * 16 + lr) * WAT_K + kb]);
      bf16x8_t wl = *reinterpret_cast<const bf16x8_t*>(&eaTL[(nt * 16 + lr) * WAT_K + kb]);
      acc = __builtin_amdgcn_mfma_f32_16x16x32_bf16(ah, wh, acc, 0, 0, 0);
      acc = __builtin_amdgcn_mfma_f32_16x16x32_bf16(al, wh, acc, 0, 0, 0);
      acc = __builtin_amdgcn_mfma_f32_16x16x32_bf16(ah, wl, acc, 0, 0, 0);
    }
    const int q = nt * 16 + lr;
    if (q < QD_) {
      const float bb = ea_b[q], qq = ea_q[q];
      #pragma unroll
      for (int i = 0; i < 4; ++i) {
        const int r = kg * 4 + i;
        if (r < E_) atomicAdd(&sSc[r], tanhf(acc[i] + bb) * qq);
      }
    }
  }
  __syncthreads();

  if (wave == 0) {
    const float v = (lane < E_) ? sSc[lane] : -1e30f;
    float mx = v;
    #pragma unroll
    for (int off = 32; off > 0; off >>= 1) mx = fmaxf(mx, __shfl_xor(mx, off));
    const float e = (lane < E_) ? __expf(v - mx) : 0.f;
    float s = e;
    #pragma unroll
    for (int off = 32; off > 0; off >>= 1) s += __shfl_xor(s, off);
    if (lane < E_) sAlpha[lane] = e / s;
  }
  __syncthreads();

  if (tid < MD_) {
    const int d = tid;
    float acc = 0.f;
    #pragma unroll
    for (int i = 0; i < E_; ++i) acc += sAlpha[i] * sR[i * SOUT_STR + d];
    ent_rep[(size_t)b * MD_ + d] = tanhf(acc);
  }
}

// ---------------------------------------------------------------------------
__global__ __launch_bounds__(256) void catsub_kernel(
    const int* __restrict__ cat_idx, const int* __restrict__ sub_idx,
    const float* __restrict__ emb_cat, const float* __restrict__ fc1_w, const float* __restrict__ fc1_b,
    const float* __restrict__ emb_sub, const float* __restrict__ fc2_w, const float* __restrict__ fc2_b,
    float* __restrict__ cat_rep, float* __restrict__ sub_rep)
{
  int idx = blockIdx.x * 256 + threadIdx.x;
  const int total = B_ * MD_;
  if (idx < total) {
    const int b = idx / MD_, d = idx - (idx / MD_) * MD_;
    const float* row = emb_cat + (size_t)cat_idx[b] * CD_;
    float acc = fc1_b[d];
    #pragma unroll
    for (int k = 0; k < CD_; ++k) acc += row[k] * fc1_w[k * MD_ + d];
    cat_rep[idx] = tanhf(acc);
  } else {
    idx -= total;
    if (idx < total) {
      const int b = idx / MD_, d = idx - (idx / MD_) * MD_;
      const float* row = emb_sub + (size_t)sub_idx[b] * SD_;
      float acc = fc2_b[d];
      #pragma unroll
      for (int k = 0; k < SD_; ++k) acc += row[k] * fc2_w[k * MD_ + d];
      sub_rep[idx] = tanhf(acc);
    }
  }
}

// ---------------------------------------------------------------------------
__global__ __launch_bounds__(256) void fuse_kernel(
    const float* __restrict__ word_rep, const float* __restrict__ ent_rep,
    const float* __restrict__ cat_rep, const float* __restrict__ sub_rep,
    const float* __restrict__ na_w, const float* __restrict__ na_b, const float* __restrict__ na_q,
    float* __restrict__ out)
{
  __shared__ float sViews[4][MD_];
  __shared__ float sSc[4];
  __shared__ float sAlpha[4];
  const int b = blockIdx.x, tid = threadIdx.x;
  for (int d = tid; d < MD_; d += 256) {
    sViews[0][d] = word_rep[(size_t)b * MD_ + d];
    sViews[1][d] = ent_rep[(size_t)b * MD_ + d];
    sViews[2][d] = cat_rep[(size_t)b * MD_ + d];
    sViews[3][d] = sub_rep[(size_t)b * MD_ + d];
  }
  if (tid < 4) sSc[tid] = 0.f;
  __syncthreads();
  for (int id = tid; id < 4 * QD_; id += 256) {
    const int v = id / QD_, q = id - (id / QD_) * QD_;
    float acc = na_b[q];
    #pragma unroll 4
    for (int d = 0; d < MD_; ++d) acc += sViews[v][d] * na_w[d * QD_ + q];
    atomicAdd(&sSc[v], tanhf(acc) * na_q[q]);
  }
  __syncthreads();
  if (tid == 0) {
    float mx = -1e30f;
    for (int v = 0; v < 4; ++v) mx = fmaxf(mx, sSc[v]);
    float sum = 0.f;
    for (int v = 0; v < 4; ++v) { const float e = __expf(sSc[v] - mx); sAlpha[v] = e; sum += e; }
    const float inv = 1.f / sum;
    for (int v = 0; v < 4; ++v) sAlpha[v] *= inv;
  }
  __syncthreads();
  for (int d = tid; d < MD_; d += 256) {
    const float acc = sAlpha[0] * sViews[0][d] + sAlpha[1] * sViews[1][d] +
                      sAlpha[2] * sViews[2][d] + sAlpha[3] * sViews[3][d];
    out[(size_t)b * MD_ + d] = tanhf(acc);
  }
}

// ---------------------------------------------------------------------------
extern "C" void kernel_launch(void* const* d_in, const int* in_sizes, int n_in,
                              void* d_out, int out_size, void* d_ws, size_t ws_size,
                              hipStream_t stream) {
  const float* X        = (const float*)d_in[0];
  const float* Ein      = (const float*)d_in[1];
  const int*   cat_idx  = (const int*)d_in[2];
  const int*   sub_idx  = (const int*)d_in[3];
  const float* emb_cat  = (const float*)d_in[4];
  const float* fc1_w    = (const float*)d_in[5];
  const float* fc1_b    = (const float*)d_in[6];
  const float* emb_sub  = (const float*)d_in[7];
  const float* fc2_w    = (const float*)d_in[8];
  const float* fc2_b    = (const float*)d_in[9];
  const float* wq       = (const float*)d_in[10];
  const float* bq       = (const float*)d_in[11];
  const float* wk       = (const float*)d_in[12];
  const float* bk       = (const float*)d_in[13];
  const float* wv       = (const float*)d_in[14];
  const float* bv       = (const float*)d_in[15];
  const float* ln_g     = (const float*)d_in[16];
  const float* ln_b     = (const float*)d_in[17];
  const float* wa_w     = (const float*)d_in[18];
  const float* wa_b     = (const float*)d_in[19];
  const float* wa_q     = (const float*)d_in[20];
  const float* fc3_w    = (const float*)d_in[21];
  const float* fc3_b    = (const float*)d_in[22];
  const float* gcn_A    = (const float*)d_in[23];
  const float* gcn_w    = (const float*)d_in[24];
  const float* gcn_b    = (const float*)d_in[25];
  const float* ea_w     = (const float*)d_in[26];
  const float* ea_b     = (const float*)d_in[27];
  const float* ea_q     = (const float*)d_in[28];
  const float* na_w     = (const float*)d_in[29];
  const float* na_b     = (const float*)d_in[30];
  const float* na_q     = (const float*)d_in[31];

  float* out = (float*)d_out;
  const size_t BM = (size_t)B_ * MD_;
  float* word_rep = (float*)d_ws;
  float* ent_rep  = word_rep + BM;
  float* cat_rep  = ent_rep + BM;
  float* sub_rep  = cat_rep + BM;
  ushort_t* Wt    = (ushort_t*)(sub_rep + BM);
  ushort_t* Wat   = Wt + N_WT;
  ushort_t* fc3TH = Wat + N_WAT;
  ushort_t* fc3TL = fc3TH + N_FC3T;
  ushort_t* gcnTH = fc3TL + N_FC3T;
  ushort_t* gcnTL = gcnTH + N_GCNT;
  ushort_t* eaTH  = gcnTL + N_GCNT;
  ushort_t* eaTL  = eaTH + N_EAT;

  {
    const int total = N_WT + N_WAT + N_FC3T + N_GCNT + N_EAT;
    prep_weights<<<(total + 255) / 256, 256, 0, stream>>>(
        wq, wk, wv, wa_w, fc3_w, gcn_w, ea_w,
        Wt, Wat, fc3TH, fc3TL, gcnTH, gcnTL, eaTH, eaTL);
  }
  word_branch_kernel<<<B_, 1024, 0, stream>>>(X, Wt, Wat, bq, bk, bv,
                                              ln_g, ln_b, wa_b, wa_q, word_rep);
  entity_branch_kernel<<<B_, 512, 0, stream>>>(Ein, fc3TH, fc3TL, fc3_b, gcn_A,
                                               gcnTH, gcnTL, gcn_b,
                                               ln_g, ln_b, eaTH, eaTL, ea_b, ea_q, ent_rep);
  catsub_kernel<<<(2 * B_ * MD_) / 256, 256, 0, stream>>>(cat_idx, sub_idx,
                                                          emb_cat, fc1_w, fc1_b,
                                                          emb_sub, fc2_w, fc2_b,
                                                          cat_rep, sub_rep);
  fuse_kernel<<<B_, 256, 0, stream>>>(word_rep, ent_rep, cat_rep, sub_rep,
                                      na_w, na_b, na_q, out);
}